// Round 1
// baseline (332.922 us; speedup 1.0000x reference)
//
#include <hip/hip_runtime.h>

#define T_DIM 2048
#define D_DIM 1024
#define H_DIM 1024
#define B_DIM 4

typedef __attribute__((ext_vector_type(8))) __bf16 bf16x8;
typedef __attribute__((ext_vector_type(4))) float f32x4;

__device__ __forceinline__ unsigned short f2b(float f) {
  union { float f; unsigned int u; } x; x.f = f;
  unsigned int r = x.u + 0x7fffu + ((x.u >> 16) & 1u);
  return (unsigned short)(r >> 16);
}

__device__ __forceinline__ void async16(unsigned short* l, const unsigned short* g) {
  __builtin_amdgcn_global_load_lds((const __attribute__((address_space(1))) void*)g,
                                   (__attribute__((address_space(3))) void*)l,
                                   16, 0, 0);
}

// ---------------- f32 -> bf16 convert (weights) ----------------
__global__ __launch_bounds__(256) void cvt_kernel(const float* __restrict__ in,
                                                  unsigned short* __restrict__ out, int n4) {
  int i = blockIdx.x * 256 + threadIdx.x;
  if (i >= n4) return;
  float4 v = ((const float4*)in)[i];
  ushort4 o;
  o.x = f2b(v.x); o.y = f2b(v.y); o.z = f2b(v.z); o.w = f2b(v.w);
  ((ushort4*)out)[i] = o;
}

// ---------------- tiled transpose (+cvt to bf16) ----------------
// in: [Z][R][C] (TIN = float or ushort-bf16) -> out: [Z][C][R] bf16
template <typename TIN>
__global__ __launch_bounds__(256) void transpose_bf16_kernel(const TIN* __restrict__ in,
                                                             unsigned short* __restrict__ out,
                                                             int R, int C) {
  __shared__ TIN tile[32][33];
  size_t boff = (size_t)blockIdx.z * R * C;
  int c0 = blockIdx.x * 32, r0 = blockIdx.y * 32;
  int tx = threadIdx.x & 31, ty = threadIdx.x >> 5;
  #pragma unroll
  for (int i = 0; i < 32; i += 8)
    tile[ty + i][tx] = in[boff + (size_t)(r0 + ty + i) * C + (c0 + tx)];
  __syncthreads();
  #pragma unroll
  for (int i = 0; i < 32; i += 8) {
    TIN v = tile[tx][ty + i];
    unsigned short b;
    if constexpr (sizeof(TIN) == 4) b = f2b((float)v);
    else b = (unsigned short)v;
    out[boff + (size_t)(c0 + ty + i) * R + (r0 + tx)] = b;
  }
}

// ---------------- B^T GEMM: C[i,j] = sum_k A[i,k]*B[j,k] (+bias[j]) ----------------
// 128x128 tile, BK=32, 4 waves (2x2 of 64x64), mfma_f32_16x16x32_bf16.
// OMODE: 1 = bf16 out, 2 = f32 out, 3 = both.
// SKIP: 0 none; 1 skip blocks with bn<bm (logits, upper-tri in [s][t]); 2 causal K-limit (PV).
template <int OMODE, bool BIAS, int SKIP>
__global__ __launch_bounds__(256)
void gemm_bt_kernel(const unsigned short* __restrict__ A, const unsigned short* __restrict__ Bm,
                    const float* __restrict__ bias,
                    float* __restrict__ Cf, unsigned short* __restrict__ Cb,
                    int M, int N, int K,
                    size_t sAb, size_t sBb, size_t sCb) {
  constexpr int BM = 128, BN = 128, BK = 32;
  int bn = blockIdx.x, bm = blockIdx.y, bz = blockIdx.z;
  if (SKIP == 1 && bn < bm) return;
  A  += (size_t)bz * sAb + (size_t)bm * BM * K;
  Bm += (size_t)bz * sBb + (size_t)bn * BN * K;
  size_t coff = (size_t)bz * sCb;

  __shared__ unsigned short ldsA[BM * BK];
  __shared__ unsigned short ldsB[BN * BK];

  int tid = threadIdx.x;
  int lane = tid & 63, wid = tid >> 6;
  int wr = wid >> 1, wc = wid & 1;
  int lo = lane & 15, hi = lane >> 4;

  f32x4 acc[4][4] = {};

  // staging: 256 threads x 2 x 16B chunks per operand tile (8192 B each)
  int so0 = tid * 16, so1 = tid * 16 + 4096;
  int r0 = so0 >> 6, c0e = (so0 & 63) >> 1;
  int r1 = so1 >> 6, c1e = (so1 & 63) >> 1;

  int kt = K;
  if (SKIP == 2) { kt = (bm + 1) * BM; if (kt > K) kt = K; }

  for (int k0 = 0; k0 < kt; k0 += BK) {
    __syncthreads();
    async16(&ldsA[so0 >> 1], A + (size_t)r0 * K + k0 + c0e);
    async16(&ldsA[so1 >> 1], A + (size_t)r1 * K + k0 + c1e);
    async16(&ldsB[so0 >> 1], Bm + (size_t)r0 * K + k0 + c0e);
    async16(&ldsB[so1 >> 1], Bm + (size_t)r1 * K + k0 + c1e);
    __syncthreads();

    bf16x8 af[4], bg[4];
    #pragma unroll
    for (int m = 0; m < 4; m++)
      af[m] = *(const bf16x8*)((const char*)ldsA + (wr * 64 + m * 16 + lo) * 64 + hi * 16);
    #pragma unroll
    for (int n = 0; n < 4; n++)
      bg[n] = *(const bf16x8*)((const char*)ldsB + (wc * 64 + n * 16 + lo) * 64 + hi * 16);
    #pragma unroll
    for (int m = 0; m < 4; m++)
      #pragma unroll
      for (int n = 0; n < 4; n++)
        acc[m][n] = __builtin_amdgcn_mfma_f32_16x16x32_bf16(af[m], bg[n], acc[m][n], 0, 0, 0);
  }

  // epilogue: C frag mapping col=lane&15, row=(lane>>4)*4+j
  #pragma unroll
  for (int n = 0; n < 4; n++) {
    int cg = bn * BN + wc * 64 + n * 16 + lo;
    float bv = BIAS ? bias[cg] : 0.f;
    #pragma unroll
    for (int m = 0; m < 4; m++) {
      int rb = bm * BM + wr * 64 + m * 16 + hi * 4;
      #pragma unroll
      for (int j = 0; j < 4; j++) {
        float v = acc[m][n][j] + bv;
        size_t idx = coff + (size_t)(rb + j) * N + cg;
        if (OMODE & 2) Cf[idx] = v;
        if (OMODE & 1) Cb[idx] = f2b(v);
      }
    }
  }
}

// ---------------- softmax stats over rows of logitsT (= axis-1 of logits) ----------------
__device__ __forceinline__ float wred_max(float v) {
  #pragma unroll
  for (int o = 32; o > 0; o >>= 1) v = fmaxf(v, __shfl_down(v, o, 64));
  return v;
}
__device__ __forceinline__ float wred_sum(float v) {
  #pragma unroll
  for (int o = 32; o > 0; o >>= 1) v += __shfl_down(v, o, 64);
  return v;
}

__global__ __launch_bounds__(256) void softmax_stats_kernel(const float* __restrict__ lg,
                                                            float* __restrict__ smax,
                                                            float* __restrict__ sinv) {
  __shared__ float sb[4];
  int row = blockIdx.x;            // b*T + s
  int s = row & (T_DIM - 1);
  const float* Lr = lg + (size_t)row * T_DIM;
  float mx = -3.4e38f;
  for (int t = threadIdx.x; t < T_DIM; t += 256)
    if (t >= s) mx = fmaxf(mx, Lr[t]);
  mx = wred_max(mx);
  if ((threadIdx.x & 63) == 0) sb[threadIdx.x >> 6] = mx;
  __syncthreads();
  mx = fmaxf(fmaxf(sb[0], sb[1]), fmaxf(sb[2], sb[3]));
  __syncthreads();
  float sum = 0.f;
  for (int t = threadIdx.x; t < T_DIM; t += 256)
    if (t >= s) sum += __expf(Lr[t] - mx);
  sum = wred_sum(sum);
  if ((threadIdx.x & 63) == 0) sb[threadIdx.x >> 6] = sum;
  __syncthreads();
  if (threadIdx.x == 0) {
    float tot = sb[0] + sb[1] + sb[2] + sb[3];
    smax[row] = mx;
    sinv[row] = 1.0f / (tot * 32.0f);   // fold 1/sqrt(D)=1/32 into the normalizer
  }
}

// ---------------- normalize + transpose: probs[t][s] bf16 from logitsT[s][t] ----------------
__global__ __launch_bounds__(256) void probs_kernel(const float* __restrict__ lg,
                                                    const float* __restrict__ smax,
                                                    const float* __restrict__ sinv,
                                                    unsigned short* __restrict__ probs) {
  int bz = blockIdx.z;
  int t0 = blockIdx.x * 32, s0 = blockIdx.y * 32;
  if (s0 >= (((t0 >> 7) + 1) << 7)) return;   // never read by the K-limited PV GEMM
  __shared__ float tile[32][33];
  int tx = threadIdx.x & 31, ty = threadIdx.x >> 5;
  const float* L = lg + (size_t)bz * T_DIM * T_DIM;
  #pragma unroll
  for (int i = 0; i < 32; i += 8)
    tile[ty + i][tx] = L[(size_t)(s0 + ty + i) * T_DIM + (t0 + tx)];
  __syncthreads();
  unsigned short* P = probs + (size_t)bz * T_DIM * T_DIM;
  #pragma unroll
  for (int i = 0; i < 32; i += 8) {
    int t = t0 + ty + i, s = s0 + tx;
    float x = tile[tx][ty + i];
    float p = (t >= s) ? __expf(x - smax[bz * T_DIM + s]) * sinv[bz * T_DIM + s] : 0.f;
    P[(size_t)t * T_DIM + s] = f2b(p);
  }
}

// ---------------- out[b][d][t] = read[b][t][d] + m[b][t][d] ----------------
__global__ __launch_bounds__(256) void out_kernel(const float* __restrict__ rd,
                                                  const float* __restrict__ mf,
                                                  float* __restrict__ out) {
  __shared__ float tile[32][33];
  int b = blockIdx.z;
  int t0 = blockIdx.x * 32, d0 = blockIdx.y * 32;
  int tx = threadIdx.x & 31, ty = threadIdx.x >> 5;
  const float* R = rd + (size_t)b * T_DIM * D_DIM;
  const float* M = mf + (size_t)b * T_DIM * D_DIM;
  #pragma unroll
  for (int i = 0; i < 32; i += 8) {
    size_t o = (size_t)(t0 + ty + i) * D_DIM + (d0 + tx);
    tile[ty + i][tx] = R[o] + M[o];
  }
  __syncthreads();
  float* O = out + (size_t)b * D_DIM * T_DIM;
  #pragma unroll
  for (int i = 0; i < 32; i += 8)
    O[(size_t)(d0 + ty + i) * T_DIM + (t0 + tx)] = tile[tx][ty + i];
}

extern "C" void kernel_launch(void* const* d_in, const int* in_sizes, int n_in,
                              void* d_out, int out_size, void* d_ws, size_t ws_size,
                              hipStream_t stream) {
  const float* minibatch = (const float*)d_in[0];
  const float* emb_w   = (const float*)d_in[1];
  const float* emb_b   = (const float*)d_in[2];
  const float* key_w   = (const float*)d_in[3];
  const float* key_b   = (const float*)d_in[4];
  const float* query_w = (const float*)d_in[5];
  const float* query_b = (const float*)d_in[6];
  const float* value_w = (const float*)d_in[7];
  const float* value_b = (const float*)d_in[8];
  float* out = (float*)d_out;

  char* ws = (char*)d_ws;
  const size_t MB = 1ull << 20;
  // Layout (~201 MiB total, with aliasing):
  unsigned short* wbf_emb = (unsigned short*)(ws + 0 * MB);
  unsigned short* wbf_key = (unsigned short*)(ws + 2 * MB);
  unsigned short* wbf_qry = (unsigned short*)(ws + 4 * MB);
  unsigned short* wbf_val = (unsigned short*)(ws + 6 * MB);
  float*          m_f32   = (float*)(ws + 8 * MB);    // 32 MB, live to end
  unsigned short* xT      = (unsigned short*)(ws + 40 * MB);  // 16 MB (dead after GEMM1)
  unsigned short* m_bf    = (unsigned short*)(ws + 56 * MB);  // 16 MB (dead after V GEMM)
  unsigned short* probs   = (unsigned short*)(ws + 40 * MB);  // 32 MB, aliases xT+m_bf
  unsigned short* K_bf    = (unsigned short*)(ws + 72 * MB);  // 16 MB (dead after logits)
  unsigned short* Q_bf    = (unsigned short*)(ws + 88 * MB);  // 16 MB (dead after logits)
  float*          read_f  = (float*)(ws + 72 * MB);   // 32 MB, aliases K_bf+Q_bf
  unsigned short* V_bf    = (unsigned short*)(ws + 104 * MB); // 16 MB
  unsigned short* VT_bf   = (unsigned short*)(ws + 120 * MB); // 16 MB
  float*          logitsT = (float*)(ws + 136 * MB);  // 64 MB
  float*          smax    = (float*)(ws + 200 * MB);
  float*          sinv    = (float*)(ws + 200 * MB + 32768);

  const int BT = B_DIM * T_DIM;   // 8192
  const size_t TD = (size_t)T_DIM * D_DIM;
  const size_t TT = (size_t)T_DIM * T_DIM;

  // 1) weights -> bf16
  cvt_kernel<<<1024, 256, 0, stream>>>(emb_w,   wbf_emb, (D_DIM * H_DIM) / 4);
  cvt_kernel<<<1024, 256, 0, stream>>>(key_w,   wbf_key, (D_DIM * D_DIM) / 4);
  cvt_kernel<<<1024, 256, 0, stream>>>(query_w, wbf_qry, (D_DIM * D_DIM) / 4);
  cvt_kernel<<<1024, 256, 0, stream>>>(value_w, wbf_val, (D_DIM * D_DIM) / 4);

  // 2) xT[b][t][h] = minibatch[b][h][t], bf16
  transpose_bf16_kernel<float><<<dim3(T_DIM / 32, H_DIM / 32, B_DIM), 256, 0, stream>>>(
      minibatch, xT, H_DIM, T_DIM);

  // 3) m = xT @ emb_w^T + emb_b  (f32 + bf16 outputs)
  gemm_bt_kernel<3, true, 0><<<dim3(D_DIM / 128, BT / 128, 1), 256, 0, stream>>>(
      xT, wbf_emb, emb_b, m_f32, m_bf, BT, D_DIM, H_DIM, 0, 0, 0);

  // 4) K/Q/V projections (bf16 out)
  gemm_bt_kernel<1, true, 0><<<dim3(D_DIM / 128, BT / 128, 1), 256, 0, stream>>>(
      m_bf, wbf_key, key_b, nullptr, K_bf, BT, D_DIM, D_DIM, 0, 0, 0);
  gemm_bt_kernel<1, true, 0><<<dim3(D_DIM / 128, BT / 128, 1), 256, 0, stream>>>(
      m_bf, wbf_qry, query_b, nullptr, Q_bf, BT, D_DIM, D_DIM, 0, 0, 0);
  gemm_bt_kernel<1, true, 0><<<dim3(D_DIM / 128, BT / 128, 1), 256, 0, stream>>>(
      m_bf, wbf_val, value_b, nullptr, V_bf, BT, D_DIM, D_DIM, 0, 0, 0);

  // 5) VT[b][d][t] = V[b][t][d]
  transpose_bf16_kernel<unsigned short><<<dim3(D_DIM / 32, T_DIM / 32, B_DIM), 256, 0, stream>>>(
      V_bf, VT_bf, T_DIM, D_DIM);

  // 6) logitsT[b][s][t] = K[b,s]·Q[b,t]  (skip blocks fully below diagonal)
  gemm_bt_kernel<2, false, 1><<<dim3(T_DIM / 128, T_DIM / 128, B_DIM), 256, 0, stream>>>(
      K_bf, Q_bf, nullptr, logitsT, nullptr, T_DIM, T_DIM, D_DIM, TD, TD, TT);

  // 7) column-softmax stats (per (b,s): max/sum over t >= s), fold 1/sqrt(D)
  softmax_stats_kernel<<<BT, 256, 0, stream>>>(logitsT, smax, sinv);

  // 8) probs[b][t][s] = exp(logitsT[s][t]-max[s])*sinv[s], 0 for t<s  (bf16, transposed)
  probs_kernel<<<dim3(T_DIM / 32, T_DIM / 32, B_DIM), 256, 0, stream>>>(
      logitsT, smax, sinv, probs);

  // 9) read[b][t][d] = sum_s probs[t,s]*VT[d,s]  (K-loop capped causally)
  gemm_bt_kernel<2, false, 2><<<dim3(D_DIM / 128, T_DIM / 128, B_DIM), 256, 0, stream>>>(
      probs, VT_bf, nullptr, read_f, nullptr, T_DIM, D_DIM, T_DIM, TT, (size_t)D_DIM * T_DIM, TD);

  // 10) out[b][d][t] = read[b][t][d] + m[b][t][d]
  out_kernel<<<dim3(T_DIM / 32, D_DIM / 32, B_DIM), 256, 0, stream>>>(read_f, m_f32, out);
}

// Round 2
// 268.198 us; speedup vs baseline: 1.2413x; 1.2413x over previous
//
#include <hip/hip_runtime.h>

#define T_DIM 2048
#define D_DIM 1024
#define H_DIM 1024
#define B_DIM 4

typedef __attribute__((ext_vector_type(8))) __bf16 bf16x8;
typedef __attribute__((ext_vector_type(4))) float f32x4;

__device__ __forceinline__ unsigned short f2b(float f) {
  union { float f; unsigned int u; } x; x.f = f;
  unsigned int r = x.u + 0x7fffu + ((x.u >> 16) & 1u);
  return (unsigned short)(r >> 16);
}
__device__ __forceinline__ float b2f(unsigned short b) {
  union { unsigned int u; float f; } x; x.u = ((unsigned int)b) << 16;
  return x.f;
}

__device__ __forceinline__ void async16(unsigned short* l, const unsigned short* g) {
  __builtin_amdgcn_global_load_lds((const __attribute__((address_space(1))) void*)g,
                                   (__attribute__((address_space(3))) void*)l,
                                   16, 0, 0);
}

// ---------------- f32 -> bf16 convert (weights) ----------------
__global__ __launch_bounds__(256) void cvt_kernel(const float* __restrict__ in,
                                                  unsigned short* __restrict__ out, int n4) {
  int i = blockIdx.x * 256 + threadIdx.x;
  if (i >= n4) return;
  float4 v = ((const float4*)in)[i];
  ushort4 o;
  o.x = f2b(v.x); o.y = f2b(v.y); o.z = f2b(v.z); o.w = f2b(v.w);
  ((ushort4*)out)[i] = o;
}

__global__ __launch_bounds__(256) void concat3_kernel(const float* __restrict__ a,
                                                      const float* __restrict__ b,
                                                      const float* __restrict__ c,
                                                      float* __restrict__ o) {
  int i = blockIdx.x * 256 + threadIdx.x;
  if (i >= 3072) return;
  o[i] = (i < 1024) ? a[i] : ((i < 2048) ? b[i - 1024] : c[i - 2048]);
}

// ---------------- tiled transpose (+cvt to bf16) ----------------
// in[z*sIn + r*inLD + c] (r<R rows, c<C cols) -> out[z*sOut + c*R + r] (bf16)
template <typename TIN>
__global__ __launch_bounds__(256) void transpose_kernel(const TIN* __restrict__ in,
                                                        unsigned short* __restrict__ out,
                                                        int inLD, size_t sIn, int R, size_t sOut) {
  __shared__ TIN tile[32][33];
  int c0 = blockIdx.x * 32, r0 = blockIdx.y * 32;
  int tx = threadIdx.x & 31, ty = threadIdx.x >> 5;
  const TIN* I = in + (size_t)blockIdx.z * sIn;
  #pragma unroll
  for (int i = 0; i < 32; i += 8)
    tile[ty + i][tx] = I[(size_t)(r0 + ty + i) * inLD + (c0 + tx)];
  __syncthreads();
  unsigned short* O = out + (size_t)blockIdx.z * sOut;
  #pragma unroll
  for (int i = 0; i < 32; i += 8) {
    TIN v = tile[tx][ty + i];
    unsigned short bb;
    if constexpr (sizeof(TIN) == 4) bb = f2b((float)v);
    else bb = (unsigned short)v;
    O[(size_t)(c0 + ty + i) * R + (r0 + tx)] = bb;
  }
}

// ============ 256x256 8-phase B^T GEMM: C[i,j] = sum_k A[i,k]*B[j,k] (+bias[j]) ============
// 512 threads = 8 waves (2M x 4N), per-wave 128x64 output, BK=64, 2 K-tiles/iter.
// LDS: 2 dbuf x (A 256x64 + B 256x64) bf16 = 128 KiB, XOR-swizzled (byte ^= (row&7)<<4).
// Counted vmcnt(2) at phases 4/8; raw s_barrier; setprio around MFMA clusters.
// OMODE: 1 = bf16 out, 2 = f32 out. SKIP: 1 = skip bn<bm (causal upper-tri in [s][t]);
// 2 = causal K-limit (PV: kt = (bm+1)*256).

#define STG_(t, op, rbase, gptr, ld)                                                     \
  do { unsigned short* d_ = &lds[(t) & 1][op][(rbase) * 64 + tid * 8];                   \
       const unsigned short* s_ = (gptr) + (size_t)((rbase) + rl0) * (ld) + (t) * 64 + ce; \
       async16(d_, s_);                                                                  \
       async16(d_ + 4096, s_ + (size_t)64 * (ld)); } while (0)

#define FRAG_(base, row, ks) \
  (*(const bf16x8*)((base) + (row) * 64 + ((((ks) << 2) | hi) ^ (lo & 7)) * 8))

#define LDA_(buf, mb)                                                  \
  _Pragma("unroll") for (int m_ = 0; m_ < 4; m_++) {                   \
    int row_ = wr * 128 + ((mb) + m_) * 16 + lo;                       \
    af[m_][0] = FRAG_(lds[buf][0], row_, 0);                           \
    af[m_][1] = FRAG_(lds[buf][0], row_, 1);                           \
  }

#define LDB_(buf, nb, bg)                                              \
  _Pragma("unroll") for (int n_ = 0; n_ < 2; n_++) {                   \
    int row_ = wc * 64 + ((nb) + n_) * 16 + lo;                        \
    bg[n_][0] = FRAG_(lds[buf][1], row_, 0);                           \
    bg[n_][1] = FRAG_(lds[buf][1], row_, 1);                           \
  }

#define MM_(mb, nb, bg)                                                              \
  __builtin_amdgcn_s_setprio(1);                                                     \
  _Pragma("unroll") for (int m_ = 0; m_ < 4; m_++)                                   \
    _Pragma("unroll") for (int n_ = 0; n_ < 2; n_++) {                               \
      acc[(mb) + m_][(nb) + n_] = __builtin_amdgcn_mfma_f32_16x16x32_bf16(           \
          af[m_][0], bg[n_][0], acc[(mb) + m_][(nb) + n_], 0, 0, 0);                 \
      acc[(mb) + m_][(nb) + n_] = __builtin_amdgcn_mfma_f32_16x16x32_bf16(           \
          af[m_][1], bg[n_][1], acc[(mb) + m_][(nb) + n_], 0, 0, 0);                 \
    }                                                                                \
  __builtin_amdgcn_s_setprio(0);

#define BAR_ asm volatile("s_barrier" ::: "memory")
#define VM2_ asm volatile("s_waitcnt vmcnt(2)" ::: "memory")
#define VM0_ asm volatile("s_waitcnt vmcnt(0)" ::: "memory")

template <int OMODE, bool BIAS, int SKIP>
__global__ __launch_bounds__(512, 2)
void gemm8_kernel(const unsigned short* __restrict__ A,
                  const unsigned short* __restrict__ Bm,
                  const float* __restrict__ bias,
                  float* __restrict__ Cf, unsigned short* __restrict__ Cb,
                  int N, int K, int lda, int ldb,
                  size_t sAb, size_t sBb, size_t sCb) {
  __shared__ unsigned short lds[2][2][256 * 64];

  // XCD-aware bijective swizzle (nwg % 8 == 0 for all our grids)
  int gx = gridDim.x;
  int nwg = gx * gridDim.y;
  int flat = blockIdx.x + gx * blockIdx.y;
  int cpx = nwg >> 3;
  int f2 = (flat & 7) * cpx + (flat >> 3);
  int bn = f2 % gx, bm = f2 / gx;
  int bz = blockIdx.z;
  if (SKIP == 1 && bn < bm) return;

  A  += (size_t)bz * sAb + (size_t)bm * 256 * lda;
  Bm += (size_t)bz * sBb + (size_t)bn * 256 * ldb;

  int tid = threadIdx.x;
  int lane = tid & 63, wid = tid >> 6;
  int wr = wid >> 2, wc = wid & 3;
  int lo = lane & 15, hi = lane >> 4;
  // staging: thread covers row rl0 (and rl0+64), bf16 col offset ce (pre-swizzled source)
  int rl0 = tid >> 3;
  int ce = 8 * ((tid & 7) ^ (rl0 & 7));

  int nt = K / 64;
  if (SKIP == 2) nt = (bm + 1) * 4;   // kt = (bm+1)*256

  bf16x8 af[4][2], bg0[2][2], bg1[2][2];
  f32x4 acc[8][4] = {};

  // prologue: tile0 fully + A0(tile1); guarantee tile0 resident (2 newest loads allowed)
  STG_(0, 0, 0, A, lda); STG_(0, 0, 128, A, lda);
  STG_(0, 1, 0, Bm, ldb); STG_(0, 1, 128, Bm, ldb);
  STG_(1, 0, 0, A, lda);
  VM2_; BAR_;

  int nIter = nt >> 1;
  for (int i = 0; i < nIter - 1; i++) {
    int ta = 2 * i, tb = 2 * i + 1;
    // P1..P4: compute tile ta (buf0); stage rest of tb + A0(ta+2)
    LDA_(0, 0) LDB_(0, 0, bg0) STG_(tb, 0, 128, A, lda); BAR_; MM_(0, 0, bg0) BAR_;
    LDB_(0, 2, bg1)            STG_(tb, 1, 0,   Bm, ldb); BAR_; MM_(0, 2, bg1) BAR_;
    LDA_(0, 4)                 STG_(tb, 1, 128, Bm, ldb); BAR_; MM_(4, 0, bg0) BAR_;
                               STG_(ta + 2, 0, 0, A, lda); BAR_; MM_(4, 2, bg1) VM2_; BAR_;
    // P5..P8: compute tile tb (buf1); stage rest of ta+2 + A0(tb+2)
    LDA_(1, 0) LDB_(1, 0, bg0) STG_(ta + 2, 0, 128, A, lda); BAR_; MM_(0, 0, bg0) BAR_;
    LDB_(1, 2, bg1)            STG_(ta + 2, 1, 0,   Bm, ldb); BAR_; MM_(0, 2, bg1) BAR_;
    LDA_(1, 4)                 STG_(ta + 2, 1, 128, Bm, ldb); BAR_; MM_(4, 0, bg0) BAR_;
                               STG_(tb + 2, 0, 0, A, lda); BAR_; MM_(4, 2, bg1) VM2_; BAR_;
  }
  { // last iteration: finish staging tile nt-1, drain, compute both
    int tb = nt - 1;
    LDA_(0, 0) LDB_(0, 0, bg0) STG_(tb, 0, 128, A, lda); BAR_; MM_(0, 0, bg0) BAR_;
    LDB_(0, 2, bg1)            STG_(tb, 1, 0,   Bm, ldb); BAR_; MM_(0, 2, bg1) BAR_;
    LDA_(0, 4)                 STG_(tb, 1, 128, Bm, ldb); BAR_; MM_(4, 0, bg0) BAR_;
                                                          BAR_; MM_(4, 2, bg1) VM0_; BAR_;
    LDA_(1, 0) LDB_(1, 0, bg0) BAR_; MM_(0, 0, bg0) BAR_;
    LDB_(1, 2, bg1)            BAR_; MM_(0, 2, bg1) BAR_;
    LDA_(1, 4)                 BAR_; MM_(4, 0, bg0) BAR_;
                               BAR_; MM_(4, 2, bg1) BAR_;
  }

  // epilogue: frag mapping col = lane&15 (lo), row = hi*4 + j (verified)
  size_t coff = (size_t)bz * sCb;
  #pragma unroll
  for (int n = 0; n < 4; n++) {
    int cg = bn * 256 + wc * 64 + n * 16 + lo;
    float bv = BIAS ? bias[cg] : 0.f;
    #pragma unroll
    for (int m = 0; m < 8; m++) {
      int rb = bm * 256 + wr * 128 + m * 16 + hi * 4;
      #pragma unroll
      for (int j = 0; j < 4; j++) {
        float v = acc[m][n][j] + bv;
        size_t idx = coff + (size_t)(rb + j) * N + cg;
        if (OMODE & 2) Cf[idx] = v;
        if (OMODE & 1) Cb[idx] = f2b(v);
      }
    }
  }
}

// ---------------- softmax stats over rows of logitsT (= axis-1 of logits) ----------------
__device__ __forceinline__ float wred_max(float v) {
  #pragma unroll
  for (int o = 32; o > 0; o >>= 1) v = fmaxf(v, __shfl_down(v, o, 64));
  return v;
}
__device__ __forceinline__ float wred_sum(float v) {
  #pragma unroll
  for (int o = 32; o > 0; o >>= 1) v += __shfl_down(v, o, 64);
  return v;
}

__global__ __launch_bounds__(256) void softmax_stats_kernel(const float* __restrict__ lg,
                                                            float* __restrict__ smax,
                                                            float* __restrict__ sinv) {
  __shared__ float sb[4];
  int row = blockIdx.x;            // b*T + s
  int s = row & (T_DIM - 1);
  const float* Lr = lg + (size_t)row * T_DIM;
  float mx = -3.4e38f;
  for (int t = threadIdx.x; t < T_DIM; t += 256)
    if (t >= s) mx = fmaxf(mx, Lr[t]);
  mx = wred_max(mx);
  if ((threadIdx.x & 63) == 0) sb[threadIdx.x >> 6] = mx;
  __syncthreads();
  mx = fmaxf(fmaxf(sb[0], sb[1]), fmaxf(sb[2], sb[3]));
  __syncthreads();
  float sum = 0.f;
  for (int t = threadIdx.x; t < T_DIM; t += 256)
    if (t >= s) sum += __expf(Lr[t] - mx);
  sum = wred_sum(sum);
  if ((threadIdx.x & 63) == 0) sb[threadIdx.x >> 6] = sum;
  __syncthreads();
  if (threadIdx.x == 0) {
    float tot = sb[0] + sb[1] + sb[2] + sb[3];
    smax[row] = mx;
    sinv[row] = 1.0f / (tot * 32.0f);   // fold 1/sqrt(D)=1/32 into the normalizer
  }
}

// ---------------- normalize + transpose: probs[t][s] bf16 from logitsT[s][t] ----------------
__global__ __launch_bounds__(256) void probs_kernel(const float* __restrict__ lg,
                                                    const float* __restrict__ smax,
                                                    const float* __restrict__ sinv,
                                                    unsigned short* __restrict__ probs) {
  int bz = blockIdx.z;
  int t0 = blockIdx.x * 32, s0 = blockIdx.y * 32;
  if (s0 >= (((t0 >> 8) + 1) << 8)) return;   // never read by the K-limited PV GEMM (256-tiles)
  __shared__ float tile[32][33];
  int tx = threadIdx.x & 31, ty = threadIdx.x >> 5;
  const float* L = lg + (size_t)bz * T_DIM * T_DIM;
  #pragma unroll
  for (int i = 0; i < 32; i += 8)
    tile[ty + i][tx] = L[(size_t)(s0 + ty + i) * T_DIM + (t0 + tx)];
  __syncthreads();
  unsigned short* P = probs + (size_t)bz * T_DIM * T_DIM;
  #pragma unroll
  for (int i = 0; i < 32; i += 8) {
    int t = t0 + ty + i, s = s0 + tx;
    float x = tile[tx][ty + i];
    float p = (t >= s) ? __expf(x - smax[bz * T_DIM + s]) * sinv[bz * T_DIM + s] : 0.f;
    P[(size_t)t * T_DIM + s] = f2b(p);
  }
}

// ---------------- out[b][d][t] = read[b][t][d] + m_bf[b][t][d] ----------------
__global__ __launch_bounds__(256) void out_kernel(const float* __restrict__ rd,
                                                  const unsigned short* __restrict__ mb,
                                                  float* __restrict__ out) {
  __shared__ float tile[32][33];
  int b = blockIdx.z;
  int t0 = blockIdx.x * 32, d0 = blockIdx.y * 32;
  int tx = threadIdx.x & 31, ty = threadIdx.x >> 5;
  const float* R = rd + (size_t)b * T_DIM * D_DIM;
  const unsigned short* M = mb + (size_t)b * T_DIM * D_DIM;
  #pragma unroll
  for (int i = 0; i < 32; i += 8) {
    size_t o = (size_t)(t0 + ty + i) * D_DIM + (d0 + tx);
    tile[ty + i][tx] = R[o] + b2f(M[o]);
  }
  __syncthreads();
  float* O = out + (size_t)b * D_DIM * T_DIM;
  #pragma unroll
  for (int i = 0; i < 32; i += 8)
    O[(size_t)(d0 + ty + i) * T_DIM + (t0 + tx)] = tile[tx][ty + i];
}

extern "C" void kernel_launch(void* const* d_in, const int* in_sizes, int n_in,
                              void* d_out, int out_size, void* d_ws, size_t ws_size,
                              hipStream_t stream) {
  const float* minibatch = (const float*)d_in[0];
  const float* emb_w   = (const float*)d_in[1];
  const float* emb_b   = (const float*)d_in[2];
  const float* key_w   = (const float*)d_in[3];
  const float* key_b   = (const float*)d_in[4];
  const float* query_w = (const float*)d_in[5];
  const float* query_b = (const float*)d_in[6];
  const float* value_w = (const float*)d_in[7];
  const float* value_b = (const float*)d_in[8];
  float* out = (float*)d_out;

  char* ws = (char*)d_ws;
  const size_t MB = 1ull << 20;
  // Layout (~186 MiB with aliasing):
  unsigned short* wbf_emb = (unsigned short*)(ws + 0 * MB);    // 2 MB
  unsigned short* wbf_kqv = (unsigned short*)(ws + 2 * MB);    // 6 MB [key|query|value] rows
  float*          kqv_b   = (float*)(ws + 8 * MB);             // 12 KB
  unsigned short* m_bf    = (unsigned short*)(ws + 9 * MB);    // 16 MB, live to end
  unsigned short* KQV     = (unsigned short*)(ws + 25 * MB);   // 48 MB (dead after logits)
  float*          read_f  = (float*)(ws + 25 * MB);            // 32 MB, aliases KQV
  unsigned short* VT_bf   = (unsigned short*)(ws + 73 * MB);   // 16 MB
  float*          logitsT = (float*)(ws + 89 * MB);            // 64 MB
  unsigned short* xT      = (unsigned short*)(ws + 153 * MB);  // 16 MB (dead after emb GEMM)
  unsigned short* probs   = (unsigned short*)(ws + 153 * MB);  // 32 MB, aliases xT
  float*          smax    = (float*)(ws + 186 * MB);
  float*          sinv    = (float*)(ws + 186 * MB + 32768);

  const int BT = B_DIM * T_DIM;   // 8192
  const size_t TT = (size_t)T_DIM * T_DIM;

  // 1) weights -> bf16 (K/Q/V merged into [3072][1024]); bias concat
  cvt_kernel<<<1024, 256, 0, stream>>>(emb_w,   wbf_emb, (D_DIM * H_DIM) / 4);
  cvt_kernel<<<1024, 256, 0, stream>>>(key_w,   wbf_kqv,                     (D_DIM * D_DIM) / 4);
  cvt_kernel<<<1024, 256, 0, stream>>>(query_w, wbf_kqv + 1024 * 1024,       (D_DIM * D_DIM) / 4);
  cvt_kernel<<<1024, 256, 0, stream>>>(value_w, wbf_kqv + 2 * 1024 * 1024,   (D_DIM * D_DIM) / 4);
  concat3_kernel<<<12, 256, 0, stream>>>(key_b, query_b, value_b, kqv_b);

  // 2) xT[b][t][h] = minibatch[b][h][t], bf16
  transpose_kernel<float><<<dim3(T_DIM / 32, H_DIM / 32, B_DIM), 256, 0, stream>>>(
      minibatch, xT, T_DIM, (size_t)H_DIM * T_DIM, H_DIM, (size_t)T_DIM * H_DIM);

  // 3) m = xT @ emb_w^T + emb_b  (bf16)
  gemm8_kernel<1, true, 0><<<dim3(D_DIM / 256, BT / 256, 1), 512, 0, stream>>>(
      xT, wbf_emb, emb_b, nullptr, m_bf, D_DIM, H_DIM, H_DIM, H_DIM, 0, 0, 0);

  // 4) KQV = m @ [Wk;Wq;Wv]^T + b  (bf16, [8192][3072])
  gemm8_kernel<1, true, 0><<<dim3(3072 / 256, BT / 256, 1), 512, 0, stream>>>(
      m_bf, wbf_kqv, kqv_b, nullptr, KQV, 3072, D_DIM, D_DIM, D_DIM, 0, 0, 0);

  // 5) VT[b][d][t] = V[b][t][d]  (V = KQV cols 2048..3071)
  transpose_kernel<unsigned short><<<dim3(D_DIM / 32, T_DIM / 32, B_DIM), 256, 0, stream>>>(
      KQV + 2048, VT_bf, 3072, (size_t)T_DIM * 3072, T_DIM, (size_t)D_DIM * T_DIM);

  // 6) logitsT[b][s][t] = K[b,s]·Q[b,t]  (skip blocks fully below diagonal)
  gemm8_kernel<2, false, 1><<<dim3(T_DIM / 256, T_DIM / 256, B_DIM), 512, 0, stream>>>(
      KQV, KQV + 1024, nullptr, logitsT, nullptr, T_DIM, D_DIM, 3072, 3072,
      (size_t)T_DIM * 3072, (size_t)T_DIM * 3072, TT);

  // 7) column-softmax stats (per (b,s): max/sum over t >= s), fold 1/sqrt(D)
  softmax_stats_kernel<<<BT, 256, 0, stream>>>(logitsT, smax, sinv);

  // 8) probs[b][t][s] = exp(logitsT[s][t]-max[s])*sinv[s], 0 for t<s  (bf16, transposed)
  probs_kernel<<<dim3(T_DIM / 32, T_DIM / 32, B_DIM), 256, 0, stream>>>(
      logitsT, smax, sinv, probs);

  // 9) read[b][t][d] = sum_s probs[t,s]*VT[d,s]  (K-loop capped causally)
  gemm8_kernel<2, false, 2><<<dim3(D_DIM / 256, T_DIM / 256, B_DIM), 512, 0, stream>>>(
      probs, VT_bf, nullptr, read_f, nullptr, D_DIM, T_DIM, T_DIM, T_DIM,
      TT, (size_t)D_DIM * T_DIM, (size_t)T_DIM * D_DIM);

  // 10) out[b][d][t] = read[b][t][d] + m[b][t][d]
  out_kernel<<<dim3(T_DIM / 32, D_DIM / 32, B_DIM), 256, 0, stream>>>(read_f, m_bf, out);
}

// Round 3
// 236.909 us; speedup vs baseline: 1.4053x; 1.1321x over previous
//
#include <hip/hip_runtime.h>

#define T_DIM 2048
#define D_DIM 1024
#define H_DIM 1024
#define B_DIM 4

typedef __attribute__((ext_vector_type(8))) __bf16 bf16x8;
typedef __attribute__((ext_vector_type(4))) float f32x4;

__device__ __forceinline__ unsigned short f2b(float f) {
  union { float f; unsigned int u; } x; x.f = f;
  unsigned int r = x.u + 0x7fffu + ((x.u >> 16) & 1u);
  return (unsigned short)(r >> 16);
}
__device__ __forceinline__ float b2f(unsigned short b) {
  union { unsigned int u; float f; } x; x.u = ((unsigned int)b) << 16;
  return x.f;
}

__device__ __forceinline__ void async16(unsigned short* l, const unsigned short* g) {
  __builtin_amdgcn_global_load_lds((const __attribute__((address_space(1))) void*)g,
                                   (__attribute__((address_space(3))) void*)l,
                                   16, 0, 0);
}

// ---------------- fused weights prep: 4x f32->bf16 cvt + bias concat ----------------
__global__ __launch_bounds__(256) void prep_kernel(const float* __restrict__ ew,
                                                   const float* __restrict__ kw,
                                                   const float* __restrict__ qw,
                                                   const float* __restrict__ vw,
                                                   const float* __restrict__ kb,
                                                   const float* __restrict__ qb,
                                                   const float* __restrict__ vb,
                                                   unsigned short* __restrict__ oe,
                                                   unsigned short* __restrict__ okqv,
                                                   float* __restrict__ ob) {
  int bid = blockIdx.x;
  if (bid == 4096) {               // bias concat: 3072 floats = 768 float4
    #pragma unroll
    for (int k = 0; k < 3; k++) {
      int f4 = threadIdx.x + k * 256;
      int fi = f4 * 4;
      const float* src = fi < 1024 ? kb + fi : (fi < 2048 ? qb + (fi - 1024) : vb + (fi - 2048));
      *(float4*)(&ob[fi]) = *(const float4*)src;
    }
    return;
  }
  int i = bid * 256 + threadIdx.x;   // float4 index over 4 x 256K
  int seg = i >> 18;
  int off = i & 262143;
  const float* in = seg == 0 ? ew : (seg == 1 ? kw : (seg == 2 ? qw : vw));
  unsigned short* out = seg == 0 ? oe : okqv + (size_t)(seg - 1) * 1048576;
  float4 v = ((const float4*)in)[off];
  ushort4 o;
  o.x = f2b(v.x); o.y = f2b(v.y); o.z = f2b(v.z); o.w = f2b(v.w);
  ((ushort4*)out)[off] = o;
}

// ---------------- tiled transpose (+cvt to bf16) ----------------
template <typename TIN>
__global__ __launch_bounds__(256) void transpose_kernel(const TIN* __restrict__ in,
                                                        unsigned short* __restrict__ out,
                                                        int inLD, size_t sIn, int R, size_t sOut) {
  __shared__ TIN tile[32][33];
  int c0 = blockIdx.x * 32, r0 = blockIdx.y * 32;
  int tx = threadIdx.x & 31, ty = threadIdx.x >> 5;
  const TIN* I = in + (size_t)blockIdx.z * sIn;
  #pragma unroll
  for (int i = 0; i < 32; i += 8)
    tile[ty + i][tx] = I[(size_t)(r0 + ty + i) * inLD + (c0 + tx)];
  __syncthreads();
  unsigned short* O = out + (size_t)blockIdx.z * sOut;
  #pragma unroll
  for (int i = 0; i < 32; i += 8) {
    TIN v = tile[tx][ty + i];
    unsigned short bb;
    if constexpr (sizeof(TIN) == 4) bb = f2b((float)v);
    else bb = (unsigned short)v;
    O[(size_t)(c0 + ty + i) * R + (r0 + tx)] = bb;
  }
}

// ============ 128x256 8-phase B^T GEMM: C[i,j] = sum_k A[i,k]*B[j,k] (+bias[j]) ============
// 512 thr = 8 waves (2M x 4N), per-wave 64x64 (acc[4][4]), BK=64, 4 phases per K-tile.
// LDS: A 2x(128x64) + B 2x(256x64) bf16 = 96 KiB, XOR-swizzled. Counted vmcnt(4).
// Staging unit = 8KB = 64 rows (one async16/thread). A-tile = 2 units, B-tile = 4 units.
// Ledger: entering G(t): t resident, A(t+1)+B(t+1)u01 in flight(<=4). G(t) stages:
//   P1: B(t+1)u2; P2: B(t+1)u3; P4: A(t+2)u0,u1 + B(t+2)u0,u1, then vmcnt(4).
// OMODE: 1 bf16 C; 2 f32 C; 4 PV-fused out[b][d][t] = acc + m_res (transposed write).
// SKIP: 1 causal block skip (logits [s][t]); 2 causal K-limit (PV: nt=(bm+1)*2).

#define BAR_ asm volatile("s_barrier" ::: "memory")
#define VM4_ asm volatile("s_waitcnt vmcnt(4)" ::: "memory")
#define VM0_ asm volatile("s_waitcnt vmcnt(0)" ::: "memory")

#define STGA(t, u) async16(ldsA + ((t) & 1) * 8192 + (u) * 4096 + tid * 8, \
                           A + (size_t)((u) * 64 + rl0) * lda + (t) * 64 + ce)
#define STGB(t, u) async16(ldsB + ((t) & 1) * 16384 + (u) * 4096 + tid * 8, \
                           Bm + (size_t)((u) * 64 + rl0) * ldb + (t) * 64 + ce)

#define FRG(base, row, ks) \
  (*(const bf16x8*)((base) + (row) * 64 + ((((ks) << 2) | hi) ^ (lo & 7)) * 8))

#define LDA01(bA) { af01[0][0] = FRG(bA, wr * 64 + lo, 0);      af01[0][1] = FRG(bA, wr * 64 + lo, 1); \
                    af01[1][0] = FRG(bA, wr * 64 + 16 + lo, 0); af01[1][1] = FRG(bA, wr * 64 + 16 + lo, 1); }
#define LDA23(bA) { af23[0][0] = FRG(bA, wr * 64 + 32 + lo, 0); af23[0][1] = FRG(bA, wr * 64 + 32 + lo, 1); \
                    af23[1][0] = FRG(bA, wr * 64 + 48 + lo, 0); af23[1][1] = FRG(bA, wr * 64 + 48 + lo, 1); }
#define LDB01(bB) { bg01[0][0] = FRG(bB, wc * 64 + lo, 0);      bg01[0][1] = FRG(bB, wc * 64 + lo, 1); \
                    bg01[1][0] = FRG(bB, wc * 64 + 16 + lo, 0); bg01[1][1] = FRG(bB, wc * 64 + 16 + lo, 1); }
#define LDB23(bB) { bg23[0][0] = FRG(bB, wc * 64 + 32 + lo, 0); bg23[0][1] = FRG(bB, wc * 64 + 32 + lo, 1); \
                    bg23[1][0] = FRG(bB, wc * 64 + 48 + lo, 0); bg23[1][1] = FRG(bB, wc * 64 + 48 + lo, 1); }

#define MMQ(MB, NB, AF, BG)                                                          \
  __builtin_amdgcn_s_setprio(1);                                                     \
  _Pragma("unroll") for (int mi = 0; mi < 2; mi++)                                   \
    _Pragma("unroll") for (int ni = 0; ni < 2; ni++) {                               \
      acc[(MB) + mi][(NB) + ni] = __builtin_amdgcn_mfma_f32_16x16x32_bf16(           \
          AF[mi][0], BG[ni][0], acc[(MB) + mi][(NB) + ni], 0, 0, 0);                 \
      acc[(MB) + mi][(NB) + ni] = __builtin_amdgcn_mfma_f32_16x16x32_bf16(           \
          AF[mi][1], BG[ni][1], acc[(MB) + mi][(NB) + ni], 0, 0, 0);                 \
    }                                                                                \
  __builtin_amdgcn_s_setprio(0);

template <int OMODE, bool BIAS, int SKIP>
__global__ __launch_bounds__(512, 2)
void gemm8_kernel(const unsigned short* __restrict__ A,
                  const unsigned short* __restrict__ Bm,
                  const float* __restrict__ bias,
                  float* __restrict__ Cf, unsigned short* __restrict__ Cb,
                  const unsigned short* __restrict__ mres,
                  int N, int K, int lda, int ldb,
                  size_t sAb, size_t sBb, size_t sCb) {
  __shared__ __align__(16) unsigned short smem[49152];
  unsigned short* ldsA = smem;            // 2 x 128x64
  unsigned short* ldsB = smem + 16384;    // 2 x 256x64

  // XCD-aware bijective swizzle (nwg % 8 == 0 for all our grids)
  int gx = gridDim.x;
  int nwg = gx * gridDim.y;
  int flat = blockIdx.x + gx * blockIdx.y;
  int cpx = nwg >> 3;
  int f2 = (flat & 7) * cpx + (flat >> 3);
  int bn = f2 % gx, bm = f2 / gx;
  int bz = blockIdx.z;
  if (SKIP == 1 && bn * 2 + 1 < bm) return;   // block's max t < min s -> all masked

  A  += (size_t)bz * sAb + (size_t)bm * 128 * lda;
  Bm += (size_t)bz * sBb + (size_t)bn * 256 * ldb;

  int tid = threadIdx.x;
  int lane = tid & 63, wid = tid >> 6;
  int wr = wid >> 2, wc = wid & 3;
  int lo = lane & 15, hi = lane >> 4;
  int rl0 = tid >> 3;
  int ce = 8 * ((tid & 7) ^ (rl0 & 7));   // pre-swizzled source chunk

  int nt = K / 64;
  if (SKIP == 2) nt = (bm + 1) * 2;       // kt = (bm+1)*128

  bf16x8 af01[2][2], af23[2][2], bg01[2][2], bg23[2][2];
  f32x4 acc[4][4] = {};

  // prologue: tile0 full (6u) + head of tile1 (4u); tile0 resident after vmcnt(4)
  STGA(0, 0); STGA(0, 1); STGB(0, 0); STGB(0, 1); STGB(0, 2); STGB(0, 3);
  STGA(1, 0); STGA(1, 1); STGB(1, 0); STGB(1, 1);
  VM4_; BAR_;

  for (int t = 0; t < nt - 2; t++) {
    const unsigned short* bA = ldsA + (t & 1) * 8192;
    const unsigned short* bB = ldsB + (t & 1) * 16384;
    LDA01(bA) LDB01(bB) STGB(t + 1, 2); BAR_; MMQ(0, 0, af01, bg01) BAR_;
    LDB23(bB)           STGB(t + 1, 3); BAR_; MMQ(0, 2, af01, bg23) BAR_;
    LDA23(bA)                           BAR_; MMQ(2, 0, af23, bg01) BAR_;
    STGA(t + 2, 0); STGA(t + 2, 1); STGB(t + 2, 0); STGB(t + 2, 1);
                                        BAR_; MMQ(2, 2, af23, bg23) VM4_; BAR_;
  }
  { // G(nt-2): finish staging B(nt-1), full drain at P4
    int tq = nt - 2;
    const unsigned short* bA = ldsA + (tq & 1) * 8192;
    const unsigned short* bB = ldsB + (tq & 1) * 16384;
    LDA01(bA) LDB01(bB) STGB(tq + 1, 2); BAR_; MMQ(0, 0, af01, bg01) BAR_;
    LDB23(bB)           STGB(tq + 1, 3); BAR_; MMQ(0, 2, af01, bg23) BAR_;
    LDA23(bA)                            BAR_; MMQ(2, 0, af23, bg01) BAR_;
                                         BAR_; MMQ(2, 2, af23, bg23) VM0_; BAR_;
  }
  { // G(nt-1): pure compute
    int tq = nt - 1;
    const unsigned short* bA = ldsA + (tq & 1) * 8192;
    const unsigned short* bB = ldsB + (tq & 1) * 16384;
    LDA01(bA) LDB01(bB) BAR_; MMQ(0, 0, af01, bg01) BAR_;
    LDB23(bB)           BAR_; MMQ(0, 2, af01, bg23) BAR_;
    LDA23(bA)           BAR_; MMQ(2, 0, af23, bg01) BAR_;
                        BAR_; MMQ(2, 2, af23, bg23) BAR_;
  }

  // ---------------- epilogue: LDS retile -> coalesced 16B stores ----------------
  __syncthreads();
  int row0 = bm * 128, col0 = bn * 256;
  size_t coff = (size_t)bz * sCb;

  if (OMODE == 1) {
    unsigned short* ep = smem;   // [128][264] padded
    #pragma unroll
    for (int n = 0; n < 4; n++) {
      int cl = wc * 64 + n * 16 + lo;
      float bv = BIAS ? bias[col0 + cl] : 0.f;
      #pragma unroll
      for (int m = 0; m < 4; m++) {
        int rl = wr * 64 + m * 16 + hi * 4;
        #pragma unroll
        for (int j = 0; j < 4; j++)
          ep[(rl + j) * 264 + cl] = f2b(acc[m][n][j] + bv);
      }
    }
    __syncthreads();
    #pragma unroll
    for (int it = 0; it < 8; it++) {
      int idx = it * 512 + tid, r = idx >> 5, c = idx & 31;
      *(uint4*)(Cb + coff + (size_t)(row0 + r) * N + col0 + c * 8) =
          *(const uint4*)(ep + r * 264 + c * 8);
    }
  } else if (OMODE == 2) {
    float* ep = (float*)smem;    // [64][260] padded
    #pragma unroll
    for (int half = 0; half < 2; half++) {
      __syncthreads();
      if (wr == half) {
        #pragma unroll
        for (int n = 0; n < 4; n++) {
          int cl = wc * 64 + n * 16 + lo;
          #pragma unroll
          for (int m = 0; m < 4; m++) {
            int rl = m * 16 + hi * 4;
            #pragma unroll
            for (int j = 0; j < 4; j++) ep[(rl + j) * 260 + cl] = acc[m][n][j];
          }
        }
      }
      __syncthreads();
      #pragma unroll
      for (int it = 0; it < 8; it++) {
        int idx = it * 512 + tid, r = idx >> 6, c = idx & 63;
        *(float4*)(Cf + coff + (size_t)(row0 + half * 64 + r) * N + col0 + c * 4) =
            *(const float4*)(ep + r * 260 + c * 4);
      }
    }
  } else {   // OMODE == 4: out[b][d][t] = acc + m[b][t][d], transposed coalesced write
    float* ep = (float*)smem;    // [128 d][132 t] padded
    #pragma unroll
    for (int half = 0; half < 2; half++) {
      __syncthreads();
      if ((wc >> 1) == half) {
        #pragma unroll
        for (int n = 0; n < 4; n++) {
          int cl = wc * 64 + n * 16 + lo;
          #pragma unroll
          for (int m = 0; m < 4; m++) {
            int rl = wr * 64 + m * 16 + hi * 4;
            #pragma unroll
            for (int j = 0; j < 4; j++) {
              float v = acc[m][n][j] +
                        b2f(mres[((size_t)bz * T_DIM + row0 + rl + j) * D_DIM + col0 + cl]);
              ep[(cl & 127) * 132 + rl + j] = v;
            }
          }
        }
      }
      __syncthreads();
      #pragma unroll
      for (int it = 0; it < 8; it++) {
        int idx = it * 512 + tid, r = idx >> 5, c = idx & 31;
        *(float4*)(Cf + ((size_t)bz * D_DIM + col0 + half * 128 + r) * T_DIM + row0 + c * 4) =
            *(const float4*)(ep + r * 132 + c * 4);
      }
    }
  }
}

// ---------------- softmax stats over rows of logitsT (= axis-1 of logits) ----------------
__device__ __forceinline__ float wred_max(float v) {
  #pragma unroll
  for (int o = 32; o > 0; o >>= 1) v = fmaxf(v, __shfl_down(v, o, 64));
  return v;
}
__device__ __forceinline__ float wred_sum(float v) {
  #pragma unroll
  for (int o = 32; o > 0; o >>= 1) v += __shfl_down(v, o, 64);
  return v;
}

__global__ __launch_bounds__(256) void softmax_stats_kernel(const float* __restrict__ lg,
                                                            float* __restrict__ smax,
                                                            float* __restrict__ sinv) {
  __shared__ float sb[4];
  int row = blockIdx.x;            // b*T + s
  int s = row & (T_DIM - 1);
  const float* Lr = lg + (size_t)row * T_DIM;
  float mx = -3.4e38f;
  for (int t = threadIdx.x; t < T_DIM; t += 256)
    if (t >= s) mx = fmaxf(mx, Lr[t]);
  mx = wred_max(mx);
  if ((threadIdx.x & 63) == 0) sb[threadIdx.x >> 6] = mx;
  __syncthreads();
  mx = fmaxf(fmaxf(sb[0], sb[1]), fmaxf(sb[2], sb[3]));
  __syncthreads();
  float sum = 0.f;
  for (int t = threadIdx.x; t < T_DIM; t += 256)
    if (t >= s) sum += __expf(Lr[t] - mx);
  sum = wred_sum(sum);
  if ((threadIdx.x & 63) == 0) sb[threadIdx.x >> 6] = sum;
  __syncthreads();
  if (threadIdx.x == 0) {
    float tot = sb[0] + sb[1] + sb[2] + sb[3];
    smax[row] = mx;
    sinv[row] = 1.0f / (tot * 32.0f);   // fold 1/sqrt(D)=1/32 into the normalizer
  }
}

// ---------------- normalize + transpose: probs[t][s] bf16 from logitsT[s][t] ----------------
__global__ __launch_bounds__(256) void probs_kernel(const float* __restrict__ lg,
                                                    const float* __restrict__ smax,
                                                    const float* __restrict__ sinv,
                                                    unsigned short* __restrict__ probs) {
  int bz = blockIdx.z;
  int t0 = blockIdx.x * 32, s0 = blockIdx.y * 32;
  if (s0 >= (((t0 >> 7) + 1) << 7)) return;   // never read by the K-limited PV GEMM (128-tiles)
  __shared__ float tile[32][33];
  int tx = threadIdx.x & 31, ty = threadIdx.x >> 5;
  const float* L = lg + (size_t)bz * T_DIM * T_DIM;
  #pragma unroll
  for (int i = 0; i < 32; i += 8)
    tile[ty + i][tx] = L[(size_t)(s0 + ty + i) * T_DIM + (t0 + tx)];
  __syncthreads();
  unsigned short* P = probs + (size_t)bz * T_DIM * T_DIM;
  #pragma unroll
  for (int i = 0; i < 32; i += 8) {
    int t = t0 + ty + i, s = s0 + tx;
    float x = tile[tx][ty + i];
    float p = (t >= s) ? __expf(x - smax[bz * T_DIM + s]) * sinv[bz * T_DIM + s] : 0.f;
    P[(size_t)t * T_DIM + s] = f2b(p);
  }
}

extern "C" void kernel_launch(void* const* d_in, const int* in_sizes, int n_in,
                              void* d_out, int out_size, void* d_ws, size_t ws_size,
                              hipStream_t stream) {
  const float* minibatch = (const float*)d_in[0];
  const float* emb_w   = (const float*)d_in[1];
  const float* emb_b   = (const float*)d_in[2];
  const float* key_w   = (const float*)d_in[3];
  const float* key_b   = (const float*)d_in[4];
  const float* query_w = (const float*)d_in[5];
  const float* query_b = (const float*)d_in[6];
  const float* value_w = (const float*)d_in[7];
  const float* value_b = (const float*)d_in[8];
  float* out = (float*)d_out;

  char* ws = (char*)d_ws;
  const size_t MB = 1ull << 20;
  unsigned short* wbf_emb = (unsigned short*)(ws + 0 * MB);    // 2 MB
  unsigned short* wbf_kqv = (unsigned short*)(ws + 2 * MB);    // 6 MB [key|query|value]
  float*          kqv_b   = (float*)(ws + 8 * MB);             // 12 KB
  unsigned short* m_bf    = (unsigned short*)(ws + 9 * MB);    // 16 MB, live to end
  unsigned short* KQV     = (unsigned short*)(ws + 25 * MB);   // 48 MB (dead after logits)
  unsigned short* VT_bf   = (unsigned short*)(ws + 73 * MB);   // 16 MB
  float*          logitsT = (float*)(ws + 89 * MB);            // 64 MB
  unsigned short* xT      = (unsigned short*)(ws + 153 * MB);  // 16 MB (dead after emb GEMM)
  unsigned short* probs   = (unsigned short*)(ws + 153 * MB);  // 32 MB, aliases xT
  float*          smax    = (float*)(ws + 186 * MB);
  float*          sinv    = (float*)(ws + 186 * MB + 32768);

  const int BT = B_DIM * T_DIM;   // 8192
  const size_t TT = (size_t)T_DIM * T_DIM;

  // 1) weights -> bf16 + bias concat (single launch)
  prep_kernel<<<4097, 256, 0, stream>>>(emb_w, key_w, query_w, value_w,
                                        key_b, query_b, value_b,
                                        wbf_emb, wbf_kqv, kqv_b);

  // 2) xT[b][t][h] = minibatch[b][h][t], bf16
  transpose_kernel<float><<<dim3(T_DIM / 32, H_DIM / 32, B_DIM), 256, 0, stream>>>(
      minibatch, xT, T_DIM, (size_t)H_DIM * T_DIM, H_DIM, (size_t)T_DIM * H_DIM);

  // 3) m = xT @ emb_w^T + emb_b  (bf16)  -- 256 blocks exact
  gemm8_kernel<1, true, 0><<<dim3(D_DIM / 256, BT / 128, 1), 512, 0, stream>>>(
      xT, wbf_emb, emb_b, nullptr, m_bf, nullptr, D_DIM, H_DIM, H_DIM, H_DIM, 0, 0, 0);

  // 4) KQV = m @ [Wk;Wq;Wv]^T + b  (bf16, [8192][3072]) -- 768 blocks = 3 exact waves
  gemm8_kernel<1, true, 0><<<dim3(3072 / 256, BT / 128, 1), 512, 0, stream>>>(
      m_bf, wbf_kqv, kqv_b, nullptr, KQV, nullptr, 3072, D_DIM, D_DIM, D_DIM, 0, 0, 0);

  // 5) VT[b][d][t] = V[b][t][d]  (V = KQV cols 2048..3071)
  transpose_kernel<unsigned short><<<dim3(D_DIM / 32, T_DIM / 32, B_DIM), 256, 0, stream>>>(
      KQV + 2048, VT_bf, 3072, (size_t)T_DIM * 3072, T_DIM, (size_t)D_DIM * T_DIM);

  // 6) logitsT[b][s][t] = K[b,s]·Q[b,t]  (causal block skip)
  gemm8_kernel<2, false, 1><<<dim3(T_DIM / 256, T_DIM / 128, B_DIM), 512, 0, stream>>>(
      KQV, KQV + 1024, nullptr, logitsT, nullptr, nullptr, T_DIM, D_DIM, 3072, 3072,
      (size_t)T_DIM * 3072, (size_t)T_DIM * 3072, TT);

  // 7) column-softmax stats (per (b,s): max/sum over t >= s), fold 1/sqrt(D)
  softmax_stats_kernel<<<BT, 256, 0, stream>>>(logitsT, smax, sinv);

  // 8) probs[b][t][s] bf16, transposed
  probs_kernel<<<dim3(T_DIM / 32, T_DIM / 32, B_DIM), 256, 0, stream>>>(
      logitsT, smax, sinv, probs);

  // 9) fused PV + residual + output transpose: out[b][d][t] = sum_s probs*VT + m
  gemm8_kernel<4, false, 2><<<dim3(D_DIM / 256, T_DIM / 128, B_DIM), 512, 0, stream>>>(
      probs, VT_bf, nullptr, out, nullptr, m_bf, D_DIM, T_DIM, T_DIM, T_DIM,
      TT, (size_t)D_DIM * T_DIM, 0);
}

// Round 4
// 235.115 us; speedup vs baseline: 1.4160x; 1.0076x over previous
//
#include <hip/hip_runtime.h>

#define T_DIM 2048
#define D_DIM 1024
#define H_DIM 1024
#define B_DIM 4

typedef __attribute__((ext_vector_type(8))) __bf16 bf16x8;
typedef __attribute__((ext_vector_type(4))) float f32x4;

__device__ __forceinline__ unsigned short f2b(float f) {
  union { float f; unsigned int u; } x; x.f = f;
  unsigned int r = x.u + 0x7fffu + ((x.u >> 16) & 1u);
  return (unsigned short)(r >> 16);
}
__device__ __forceinline__ float b2f(unsigned short b) {
  union { unsigned int u; float f; } x; x.u = ((unsigned int)b) << 16;
  return x.f;
}

__device__ __forceinline__ void async16(unsigned short* l, const unsigned short* g) {
  __builtin_amdgcn_global_load_lds((const __attribute__((address_space(1))) void*)g,
                                   (__attribute__((address_space(3))) void*)l,
                                   16, 0, 0);
}

// ---------------- fused weights prep: 4x f32->bf16 cvt + bias concat ----------------
__global__ __launch_bounds__(256) void prep_kernel(const float* __restrict__ ew,
                                                   const float* __restrict__ kw,
                                                   const float* __restrict__ qw,
                                                   const float* __restrict__ vw,
                                                   const float* __restrict__ kb,
                                                   const float* __restrict__ qb,
                                                   const float* __restrict__ vb,
                                                   unsigned short* __restrict__ oe,
                                                   unsigned short* __restrict__ okqv,
                                                   float* __restrict__ ob) {
  int bid = blockIdx.x;
  if (bid == 4096) {               // bias concat: 3072 floats = 768 float4
    #pragma unroll
    for (int k = 0; k < 3; k++) {
      int f4 = threadIdx.x + k * 256;
      int fi = f4 * 4;
      const float* src = fi < 1024 ? kb + fi : (fi < 2048 ? qb + (fi - 1024) : vb + (fi - 2048));
      *(float4*)(&ob[fi]) = *(const float4*)src;
    }
    return;
  }
  int i = bid * 256 + threadIdx.x;   // float4 index over 4 x 256K
  int seg = i >> 18;
  int off = i & 262143;
  const float* in = seg == 0 ? ew : (seg == 1 ? kw : (seg == 2 ? qw : vw));
  unsigned short* out = seg == 0 ? oe : okqv + (size_t)(seg - 1) * 1048576;
  float4 v = ((const float4*)in)[off];
  ushort4 o;
  o.x = f2b(v.x); o.y = f2b(v.y); o.z = f2b(v.z); o.w = f2b(v.w);
  ((ushort4*)out)[off] = o;
}

// ---------------- tiled transpose (+cvt to bf16) ----------------
template <typename TIN>
__global__ __launch_bounds__(256) void transpose_kernel(const TIN* __restrict__ in,
                                                        unsigned short* __restrict__ out,
                                                        int inLD, size_t sIn, int R, size_t sOut) {
  __shared__ TIN tile[32][33];
  int c0 = blockIdx.x * 32, r0 = blockIdx.y * 32;
  int tx = threadIdx.x & 31, ty = threadIdx.x >> 5;
  const TIN* I = in + (size_t)blockIdx.z * sIn;
  #pragma unroll
  for (int i = 0; i < 32; i += 8)
    tile[ty + i][tx] = I[(size_t)(r0 + ty + i) * inLD + (c0 + tx)];
  __syncthreads();
  unsigned short* O = out + (size_t)blockIdx.z * sOut;
  #pragma unroll
  for (int i = 0; i < 32; i += 8) {
    TIN v = tile[tx][ty + i];
    unsigned short bb;
    if constexpr (sizeof(TIN) == 4) bb = f2b((float)v);
    else bb = (unsigned short)v;
    O[(size_t)(c0 + ty + i) * R + (r0 + tx)] = bb;
  }
}

// ============ 128x256 B^T GEMM, 2 phases/K-tile, 16 MFMA/phase ============
// 512 thr = 8 waves (2M x 4N), per-wave 64x64 (acc[4][4]), BK=64.
// LDS: A 2x(128x64) + B 2x(256x64) bf16 = 96 KiB, XOR-swizzled. Counted vmcnt(4).
// Staging unit = 8KB (one async16/thread); A-tile 2u, B-tile 4u.
// Ledger: entry to tile t: t resident, 4 units of t+1 in flight.
//   Phase A: 12 ds_read; issue B(t+1)u2,u3 [6 in flight]; BAR; 16 MFMA; BAR.
//   Phase B: 4 ds_read; BAR; issue A(t+2)u01+B(t+2)u01 into buf cur (regions dead:
//     all B(t) reads before phase-A BAR, all A(t) reads before this BAR) [10];
//     16 MFMA; vmcnt(4) -> t+1 resident; BAR.
// OMODE: 1 bf16 C; 2 f32 C; 4 PV-fused out[b][d][t] = acc + m_res (transposed write).
// SKIP: 1 causal block skip (logits [s][t]); 2 causal K-limit (PV: nt=(bm+1)*2).

#define BAR_ asm volatile("s_barrier" ::: "memory")
#define VM4_ asm volatile("s_waitcnt vmcnt(4)" ::: "memory")
#define VM0_ asm volatile("s_waitcnt vmcnt(0)" ::: "memory")

#define STGA(t, u) async16(ldsA + ((t) & 1) * 8192 + (u) * 4096 + tid * 8, \
                           A + (size_t)((u) * 64 + rl0) * lda + (t) * 64 + ce)
#define STGB(t, u) async16(ldsB + ((t) & 1) * 16384 + (u) * 4096 + tid * 8, \
                           Bm + (size_t)((u) * 64 + rl0) * ldb + (t) * 64 + ce)

#define FRG(base, row, ks) \
  (*(const bf16x8*)((base) + (row) * 64 + ((((ks) << 2) | hi) ^ (lo & 7)) * 8))

#define LDA01(bA) { af01[0][0] = FRG(bA, wr * 64 + lo, 0);      af01[0][1] = FRG(bA, wr * 64 + lo, 1); \
                    af01[1][0] = FRG(bA, wr * 64 + 16 + lo, 0); af01[1][1] = FRG(bA, wr * 64 + 16 + lo, 1); }
#define LDA23(bA) { af23[0][0] = FRG(bA, wr * 64 + 32 + lo, 0); af23[0][1] = FRG(bA, wr * 64 + 32 + lo, 1); \
                    af23[1][0] = FRG(bA, wr * 64 + 48 + lo, 0); af23[1][1] = FRG(bA, wr * 64 + 48 + lo, 1); }
#define LDBALL(bB) \
  _Pragma("unroll") for (int n_ = 0; n_ < 4; n_++) { \
    bg[n_][0] = FRG(bB, wc * 64 + n_ * 16 + lo, 0);  \
    bg[n_][1] = FRG(bB, wc * 64 + n_ * 16 + lo, 1);  }

#define MM16(MB, AF)                                                                 \
  __builtin_amdgcn_s_setprio(1);                                                     \
  _Pragma("unroll") for (int mi = 0; mi < 2; mi++)                                   \
    _Pragma("unroll") for (int ni = 0; ni < 4; ni++) {                               \
      acc[(MB) + mi][ni] = __builtin_amdgcn_mfma_f32_16x16x32_bf16(                  \
          AF[mi][0], bg[ni][0], acc[(MB) + mi][ni], 0, 0, 0);                        \
      acc[(MB) + mi][ni] = __builtin_amdgcn_mfma_f32_16x16x32_bf16(                  \
          AF[mi][1], bg[ni][1], acc[(MB) + mi][ni], 0, 0, 0);                        \
    }                                                                                \
  __builtin_amdgcn_s_setprio(0);

template <int OMODE, bool BIAS, int SKIP>
__global__ __launch_bounds__(512, 2)
void gemm8_kernel(const unsigned short* __restrict__ A,
                  const unsigned short* __restrict__ Bm,
                  const float* __restrict__ bias,
                  float* __restrict__ Cf, unsigned short* __restrict__ Cb,
                  const unsigned short* __restrict__ mres,
                  int N, int K, int lda, int ldb,
                  size_t sAb, size_t sBb, size_t sCb) {
  __shared__ __align__(16) unsigned short smem[49152];
  unsigned short* ldsA = smem;            // 2 x 128x64
  unsigned short* ldsB = smem + 16384;    // 2 x 256x64

  // XCD-aware bijective swizzle (nwg % 8 == 0 for all our grids)
  int gx = gridDim.x;
  int nwg = gx * gridDim.y;
  int flat = blockIdx.x + gx * blockIdx.y;
  int cpx = nwg >> 3;
  int f2 = (flat & 7) * cpx + (flat >> 3);
  int bn = f2 % gx, bm = f2 / gx;
  int bz = blockIdx.z;
  if (SKIP == 1 && bn * 2 + 1 < bm) return;   // block's max t < min s -> all masked

  A  += (size_t)bz * sAb + (size_t)bm * 128 * lda;
  Bm += (size_t)bz * sBb + (size_t)bn * 256 * ldb;

  int tid = threadIdx.x;
  int lane = tid & 63, wid = tid >> 6;
  int wr = wid >> 2, wc = wid & 3;
  int lo = lane & 15, hi = lane >> 4;
  int rl0 = tid >> 3;
  int ce = 8 * ((tid & 7) ^ (rl0 & 7));   // pre-swizzled source chunk

  int nt = K / 64;
  if (SKIP == 2) nt = (bm + 1) * 2;       // kt = (bm+1)*128

  bf16x8 af01[2][2], af23[2][2], bg[4][2];
  f32x4 acc[4][4] = {};

  // prologue: tile0 full (6u) + head of tile1 (4u)
  STGA(0, 0); STGA(0, 1); STGB(0, 0); STGB(0, 1); STGB(0, 2); STGB(0, 3);
  STGA(1, 0); STGA(1, 1); STGB(1, 0); STGB(1, 1);
  VM4_; BAR_;

  for (int t = 0; t < nt - 2; t++) {
    const unsigned short* bA = ldsA + (t & 1) * 8192;
    const unsigned short* bB = ldsB + (t & 1) * 16384;
    // Phase A
    LDA01(bA) LDBALL(bB)
    STGB(t + 1, 2); STGB(t + 1, 3);
    BAR_; MM16(0, af01) BAR_;
    // Phase B
    LDA23(bA)
    BAR_;
    STGA(t + 2, 0); STGA(t + 2, 1); STGB(t + 2, 0); STGB(t + 2, 1);
    MM16(2, af23) VM4_; BAR_;
  }
  { // t = nt-2: finish staging tile nt-1, full drain at end
    int tq = nt - 2;
    const unsigned short* bA = ldsA + (tq & 1) * 8192;
    const unsigned short* bB = ldsB + (tq & 1) * 16384;
    LDA01(bA) LDBALL(bB)
    STGB(tq + 1, 2); STGB(tq + 1, 3);
    BAR_; MM16(0, af01) BAR_;
    LDA23(bA)
    BAR_; MM16(2, af23) VM0_; BAR_;
  }
  { // t = nt-1: pure compute
    int tq = nt - 1;
    const unsigned short* bA = ldsA + (tq & 1) * 8192;
    const unsigned short* bB = ldsB + (tq & 1) * 16384;
    LDA01(bA) LDBALL(bB)
    BAR_; MM16(0, af01) BAR_;
    LDA23(bA)
    BAR_; MM16(2, af23)
  }

  // ---------------- epilogue: LDS retile -> coalesced 16B stores ----------------
  __syncthreads();
  int row0 = bm * 128, col0 = bn * 256;
  size_t coff = (size_t)bz * sCb;

  if (OMODE == 1) {
    unsigned short* ep = smem;   // [128][264] padded
    #pragma unroll
    for (int n = 0; n < 4; n++) {
      int cl = wc * 64 + n * 16 + lo;
      float bv = BIAS ? bias[col0 + cl] : 0.f;
      #pragma unroll
      for (int m = 0; m < 4; m++) {
        int rl = wr * 64 + m * 16 + hi * 4;
        #pragma unroll
        for (int j = 0; j < 4; j++)
          ep[(rl + j) * 264 + cl] = f2b(acc[m][n][j] + bv);
      }
    }
    __syncthreads();
    #pragma unroll
    for (int it = 0; it < 8; it++) {
      int idx = it * 512 + tid, r = idx >> 5, c = idx & 31;
      *(uint4*)(Cb + coff + (size_t)(row0 + r) * N + col0 + c * 8) =
          *(const uint4*)(ep + r * 264 + c * 8);
    }
  } else if (OMODE == 2) {
    float* ep = (float*)smem;    // [64][260] padded
    #pragma unroll
    for (int half = 0; half < 2; half++) {
      __syncthreads();
      if (wr == half) {
        #pragma unroll
        for (int n = 0; n < 4; n++) {
          int cl = wc * 64 + n * 16 + lo;
          #pragma unroll
          for (int m = 0; m < 4; m++) {
            int rl = m * 16 + hi * 4;
            #pragma unroll
            for (int j = 0; j < 4; j++) ep[(rl + j) * 260 + cl] = acc[m][n][j];
          }
        }
      }
      __syncthreads();
      #pragma unroll
      for (int it = 0; it < 8; it++) {
        int idx = it * 512 + tid, r = idx >> 6, c = idx & 63;
        *(float4*)(Cf + coff + (size_t)(row0 + half * 64 + r) * N + col0 + c * 4) =
            *(const float4*)(ep + r * 260 + c * 4);
      }
    }
  } else {   // OMODE == 4: out[b][d][t] = acc + m[b][t][d], transposed coalesced write
    float* ep = (float*)smem;    // [128 d][132 t] padded
    #pragma unroll
    for (int half = 0; half < 2; half++) {
      __syncthreads();
      if ((wc >> 1) == half) {
        #pragma unroll
        for (int n = 0; n < 4; n++) {
          int cl = wc * 64 + n * 16 + lo;
          #pragma unroll
          for (int m = 0; m < 4; m++) {
            int rl = wr * 64 + m * 16 + hi * 4;
            #pragma unroll
            for (int j = 0; j < 4; j++) {
              float v = acc[m][n][j] +
                        b2f(mres[((size_t)bz * T_DIM + row0 + rl + j) * D_DIM + col0 + cl]);
              ep[(cl & 127) * 132 + rl + j] = v;
            }
          }
        }
      }
      __syncthreads();
      #pragma unroll
      for (int it = 0; it < 8; it++) {
        int idx = it * 512 + tid, r = idx >> 5, c = idx & 31;
        *(float4*)(Cf + ((size_t)bz * D_DIM + col0 + half * 128 + r) * T_DIM + row0 + c * 4) =
            *(const float4*)(ep + r * 132 + c * 4);
      }
    }
  }
}

// ---------------- softmax stats over rows of logitsT (= axis-1 of logits) ----------------
__device__ __forceinline__ float wred_max(float v) {
  #pragma unroll
  for (int o = 32; o > 0; o >>= 1) v = fmaxf(v, __shfl_down(v, o, 64));
  return v;
}
__device__ __forceinline__ float wred_sum(float v) {
  #pragma unroll
  for (int o = 32; o > 0; o >>= 1) v += __shfl_down(v, o, 64);
  return v;
}

__global__ __launch_bounds__(256) void softmax_stats_kernel(const float* __restrict__ lg,
                                                            float* __restrict__ smax,
                                                            float* __restrict__ sinv) {
  __shared__ float sb[4];
  int row = blockIdx.x;            // b*T + s
  int s = row & (T_DIM - 1);
  const float* Lr = lg + (size_t)row * T_DIM;
  float mx = -3.4e38f;
  for (int t = threadIdx.x; t < T_DIM; t += 256)
    if (t >= s) mx = fmaxf(mx, Lr[t]);
  mx = wred_max(mx);
  if ((threadIdx.x & 63) == 0) sb[threadIdx.x >> 6] = mx;
  __syncthreads();
  mx = fmaxf(fmaxf(sb[0], sb[1]), fmaxf(sb[2], sb[3]));
  __syncthreads();
  float sum = 0.f;
  for (int t = threadIdx.x; t < T_DIM; t += 256)
    if (t >= s) sum += __expf(Lr[t] - mx);
  sum = wred_sum(sum);
  if ((threadIdx.x & 63) == 0) sb[threadIdx.x >> 6] = sum;
  __syncthreads();
  if (threadIdx.x == 0) {
    float tot = sb[0] + sb[1] + sb[2] + sb[3];
    smax[row] = mx;
    sinv[row] = 1.0f / (tot * 32.0f);   // fold 1/sqrt(D)=1/32 into the normalizer
  }
}

// ---------------- normalize + transpose: probs[t][s] bf16 from logitsT[s][t] ----------------
__global__ __launch_bounds__(256) void probs_kernel(const float* __restrict__ lg,
                                                    const float* __restrict__ smax,
                                                    const float* __restrict__ sinv,
                                                    unsigned short* __restrict__ probs) {
  int bz = blockIdx.z;
  int t0 = blockIdx.x * 32, s0 = blockIdx.y * 32;
  if (s0 >= (((t0 >> 7) + 1) << 7)) return;   // never read by the K-limited PV GEMM (128-tiles)
  __shared__ float tile[32][33];
  int tx = threadIdx.x & 31, ty = threadIdx.x >> 5;
  const float* L = lg + (size_t)bz * T_DIM * T_DIM;
  #pragma unroll
  for (int i = 0; i < 32; i += 8)
    tile[ty + i][tx] = L[(size_t)(s0 + ty + i) * T_DIM + (t0 + tx)];
  __syncthreads();
  unsigned short* P = probs + (size_t)bz * T_DIM * T_DIM;
  #pragma unroll
  for (int i = 0; i < 32; i += 8) {
    int t = t0 + ty + i, s = s0 + tx;
    float x = tile[tx][ty + i];
    float p = (t >= s) ? __expf(x - smax[bz * T_DIM + s]) * sinv[bz * T_DIM + s] : 0.f;
    P[(size_t)t * T_DIM + s] = f2b(p);
  }
}

extern "C" void kernel_launch(void* const* d_in, const int* in_sizes, int n_in,
                              void* d_out, int out_size, void* d_ws, size_t ws_size,
                              hipStream_t stream) {
  const float* minibatch = (const float*)d_in[0];
  const float* emb_w   = (const float*)d_in[1];
  const float* emb_b   = (const float*)d_in[2];
  const float* key_w   = (const float*)d_in[3];
  const float* key_b   = (const float*)d_in[4];
  const float* query_w = (const float*)d_in[5];
  const float* query_b = (const float*)d_in[6];
  const float* value_w = (const float*)d_in[7];
  const float* value_b = (const float*)d_in[8];
  float* out = (float*)d_out;

  char* ws = (char*)d_ws;
  const size_t MB = 1ull << 20;
  unsigned short* wbf_emb = (unsigned short*)(ws + 0 * MB);    // 2 MB
  unsigned short* wbf_kqv = (unsigned short*)(ws + 2 * MB);    // 6 MB [key|query|value]
  float*          kqv_b   = (float*)(ws + 8 * MB);             // 12 KB
  unsigned short* m_bf    = (unsigned short*)(ws + 9 * MB);    // 16 MB, live to end
  unsigned short* KQV     = (unsigned short*)(ws + 25 * MB);   // 48 MB (dead after logits)
  unsigned short* VT_bf   = (unsigned short*)(ws + 73 * MB);   // 16 MB
  float*          logitsT = (float*)(ws + 89 * MB);            // 64 MB
  unsigned short* xT      = (unsigned short*)(ws + 153 * MB);  // 16 MB (dead after emb GEMM)
  unsigned short* probs   = (unsigned short*)(ws + 153 * MB);  // 32 MB, aliases xT
  float*          smax    = (float*)(ws + 186 * MB);
  float*          sinv    = (float*)(ws + 186 * MB + 32768);

  const int BT = B_DIM * T_DIM;   // 8192
  const size_t TT = (size_t)T_DIM * T_DIM;

  // 1) weights -> bf16 + bias concat (single launch)
  prep_kernel<<<4097, 256, 0, stream>>>(emb_w, key_w, query_w, value_w,
                                        key_b, query_b, value_b,
                                        wbf_emb, wbf_kqv, kqv_b);

  // 2) xT[b][t][h] = minibatch[b][h][t], bf16
  transpose_kernel<float><<<dim3(T_DIM / 32, H_DIM / 32, B_DIM), 256, 0, stream>>>(
      minibatch, xT, T_DIM, (size_t)H_DIM * T_DIM, H_DIM, (size_t)T_DIM * H_DIM);

  // 3) m = xT @ emb_w^T + emb_b  (bf16)  -- 256 blocks exact
  gemm8_kernel<1, true, 0><<<dim3(D_DIM / 256, BT / 128, 1), 512, 0, stream>>>(
      xT, wbf_emb, emb_b, nullptr, m_bf, nullptr, D_DIM, H_DIM, H_DIM, H_DIM, 0, 0, 0);

  // 4) KQV = m @ [Wk;Wq;Wv]^T + b  (bf16, [8192][3072]) -- 768 blocks = 3 exact waves
  gemm8_kernel<1, true, 0><<<dim3(3072 / 256, BT / 128, 1), 512, 0, stream>>>(
      m_bf, wbf_kqv, kqv_b, nullptr, KQV, nullptr, 3072, D_DIM, D_DIM, D_DIM, 0, 0, 0);

  // 5) VT[b][d][t] = V[b][t][d]  (V = KQV cols 2048..3071)
  transpose_kernel<unsigned short><<<dim3(D_DIM / 32, T_DIM / 32, B_DIM), 256, 0, stream>>>(
      KQV + 2048, VT_bf, 3072, (size_t)T_DIM * 3072, T_DIM, (size_t)D_DIM * T_DIM);

  // 6) logitsT[b][s][t] = K[b,s]·Q[b,t]  (causal block skip)
  gemm8_kernel<2, false, 1><<<dim3(T_DIM / 256, T_DIM / 128, B_DIM), 512, 0, stream>>>(
      KQV, KQV + 1024, nullptr, logitsT, nullptr, nullptr, T_DIM, D_DIM, 3072, 3072,
      (size_t)T_DIM * 3072, (size_t)T_DIM * 3072, TT);

  // 7) column-softmax stats (per (b,s): max/sum over t >= s), fold 1/sqrt(D)
  softmax_stats_kernel<<<BT, 256, 0, stream>>>(logitsT, smax, sinv);

  // 8) probs[b][t][s] bf16, transposed
  probs_kernel<<<dim3(T_DIM / 32, T_DIM / 32, B_DIM), 256, 0, stream>>>(
      logitsT, smax, sinv, probs);

  // 9) fused PV + residual + output transpose: out[b][d][t] = sum_s probs*VT + m
  gemm8_kernel<4, false, 2><<<dim3(D_DIM / 256, T_DIM / 128, B_DIM), 512, 0, stream>>>(
      probs, VT_bf, nullptr, out, nullptr, m_bf, D_DIM, T_DIM, T_DIM, T_DIM,
      TT, (size_t)D_DIM * T_DIM, 0);
}

// Round 5
// 225.299 us; speedup vs baseline: 1.4777x; 1.0436x over previous
//
#include <hip/hip_runtime.h>

#define T_DIM 2048
#define D_DIM 1024
#define H_DIM 1024
#define B_DIM 4

typedef __attribute__((ext_vector_type(8))) __bf16 bf16x8;
typedef __attribute__((ext_vector_type(4))) float f32x4;

__device__ __forceinline__ unsigned short f2b(float f) {
  union { float f; unsigned int u; } x; x.f = f;
  unsigned int r = x.u + 0x7fffu + ((x.u >> 16) & 1u);
  return (unsigned short)(r >> 16);
}
__device__ __forceinline__ float b2f(unsigned short b) {
  union { unsigned int u; float f; } x; x.u = ((unsigned int)b) << 16;
  return x.f;
}

__device__ __forceinline__ void async16(unsigned short* l, const unsigned short* g) {
  __builtin_amdgcn_global_load_lds((const __attribute__((address_space(1))) void*)g,
                                   (__attribute__((address_space(3))) void*)l,
                                   16, 0, 0);
}

// ---------------- fused weights prep: 4x f32->bf16 cvt + bias concat ----------------
__global__ __launch_bounds__(256) void prep_kernel(const float* __restrict__ ew,
                                                   const float* __restrict__ kw,
                                                   const float* __restrict__ qw,
                                                   const float* __restrict__ vw,
                                                   const float* __restrict__ kb,
                                                   const float* __restrict__ qb,
                                                   const float* __restrict__ vb,
                                                   unsigned short* __restrict__ oe,
                                                   unsigned short* __restrict__ okqv,
                                                   float* __restrict__ ob) {
  int bid = blockIdx.x;
  if (bid == 4096) {               // bias concat: 3072 floats = 768 float4
    #pragma unroll
    for (int k = 0; k < 3; k++) {
      int f4 = threadIdx.x + k * 256;
      int fi = f4 * 4;
      const float* src = fi < 1024 ? kb + fi : (fi < 2048 ? qb + (fi - 1024) : vb + (fi - 2048));
      *(float4*)(&ob[fi]) = *(const float4*)src;
    }
    return;
  }
  int i = bid * 256 + threadIdx.x;   // float4 index over 4 x 256K
  int seg = i >> 18;
  int off = i & 262143;
  const float* in = seg == 0 ? ew : (seg == 1 ? kw : (seg == 2 ? qw : vw));
  unsigned short* out = seg == 0 ? oe : okqv + (size_t)(seg - 1) * 1048576;
  float4 v = ((const float4*)in)[off];
  ushort4 o;
  o.x = f2b(v.x); o.y = f2b(v.y); o.z = f2b(v.z); o.w = f2b(v.w);
  ((ushort4*)out)[off] = o;
}

// ---------------- tiled transpose (+cvt to bf16) ----------------
template <typename TIN>
__global__ __launch_bounds__(256) void transpose_kernel(const TIN* __restrict__ in,
                                                        unsigned short* __restrict__ out,
                                                        int inLD, size_t sIn, int R, size_t sOut) {
  __shared__ TIN tile[32][33];
  int c0 = blockIdx.x * 32, r0 = blockIdx.y * 32;
  int tx = threadIdx.x & 31, ty = threadIdx.x >> 5;
  const TIN* I = in + (size_t)blockIdx.z * sIn;
  #pragma unroll
  for (int i = 0; i < 32; i += 8)
    tile[ty + i][tx] = I[(size_t)(r0 + ty + i) * inLD + (c0 + tx)];
  __syncthreads();
  unsigned short* O = out + (size_t)blockIdx.z * sOut;
  #pragma unroll
  for (int i = 0; i < 32; i += 8) {
    TIN v = tile[tx][ty + i];
    unsigned short bb;
    if constexpr (sizeof(TIN) == 4) bb = f2b((float)v);
    else bb = (unsigned short)v;
    O[(size_t)(c0 + ty + i) * R + (r0 + tx)] = bb;
  }
}

// ============ 128x256 B^T GEMM, triple-buffered, 1 barrier / K-tile ============
// 512 thr = 8 waves (2M x 4N), per-wave 64x64 (acc[4][4]), BK=64, 32 MFMA/K-tile/wave.
// LDS: 3 bufs x (A 128x64 + B 256x64) bf16 = 144 KiB, XOR-swizzled.
// Depth-2 prefetch ledger: prologue stages t0,t1 (12 loads), vmcnt(6) -> t0 resident.
//   Iter t: 16 ds_read_b128 from buf(t%3); stage ALL 6 units of t+2 into buf((t+2)%3)
//   (that buffer's reads lgkm-retired before the PREVIOUS barrier -> no write/read race);
//   32 MFMA (setprio-wrapped); vmcnt(6) -> t+1 resident with >= 1 full K-tile of slack
//   (~1400cy > ~900cy HBM latency); s_barrier. Tail: vmcnt(0) before last tile.
// OMODE: 1 bf16 C; 2 f32 C; 4 PV-fused out[b][d][t] = acc + m_res (transposed write).
// SKIP: 1 causal block skip (logits [s][t]); 2 causal K-limit (PV: nt=(bm+1)*2).

#define BAR_ asm volatile("s_barrier" ::: "memory")
#define VM6_ asm volatile("s_waitcnt vmcnt(6)" ::: "memory")
#define VM0_ asm volatile("s_waitcnt vmcnt(0)" ::: "memory")

#define STGA3(t, bb, u) async16(smem + (bb) * 24576 + (u) * 4096 + tid * 8, \
                                A + (size_t)((u) * 64 + rl0) * lda + (t) * 64 + ce)
#define STGB3(t, bb, u) async16(smem + (bb) * 24576 + 8192 + (u) * 4096 + tid * 8, \
                                Bm + (size_t)((u) * 64 + rl0) * ldb + (t) * 64 + ce)
#define STGTILE(t, bb) do { STGA3(t, bb, 0); STGA3(t, bb, 1); \
    STGB3(t, bb, 0); STGB3(t, bb, 1); STGB3(t, bb, 2); STGB3(t, bb, 3); } while (0)

#define FRG(base, row, ks) \
  (*(const bf16x8*)((base) + (row) * 64 + ((((ks) << 2) | hi) ^ (lo & 7)) * 8))

#define LOADFRAGS(bA, bB)                                            \
  _Pragma("unroll") for (int m_ = 0; m_ < 4; m_++) {                 \
    af[m_][0] = FRG(bA, wr * 64 + m_ * 16 + lo, 0);                  \
    af[m_][1] = FRG(bA, wr * 64 + m_ * 16 + lo, 1);                  \
  }                                                                  \
  _Pragma("unroll") for (int n_ = 0; n_ < 4; n_++) {                 \
    bg[n_][0] = FRG(bB, wc * 64 + n_ * 16 + lo, 0);                  \
    bg[n_][1] = FRG(bB, wc * 64 + n_ * 16 + lo, 1);                  \
  }

#define MFMA32_                                                          \
  __builtin_amdgcn_s_setprio(1);                                         \
  _Pragma("unroll") for (int ks_ = 0; ks_ < 2; ks_++)                    \
    _Pragma("unroll") for (int m_ = 0; m_ < 4; m_++)                     \
      _Pragma("unroll") for (int n_ = 0; n_ < 4; n_++)                   \
        acc[m_][n_] = __builtin_amdgcn_mfma_f32_16x16x32_bf16(           \
            af[m_][ks_], bg[n_][ks_], acc[m_][n_], 0, 0, 0);             \
  __builtin_amdgcn_s_setprio(0);

template <int OMODE, bool BIAS, int SKIP>
__global__ __launch_bounds__(512, 2)
void gemm8_kernel(const unsigned short* __restrict__ A,
                  const unsigned short* __restrict__ Bm,
                  const float* __restrict__ bias,
                  float* __restrict__ Cf, unsigned short* __restrict__ Cb,
                  const unsigned short* __restrict__ mres,
                  int N, int K, int lda, int ldb,
                  size_t sAb, size_t sBb, size_t sCb) {
  __shared__ __align__(16) unsigned short smem[73728];   // 3 x 48KB = 144 KiB

  // XCD-aware bijective swizzle (nwg % 8 == 0 for all our grids)
  int gx = gridDim.x;
  int nwg = gx * gridDim.y;
  int flat = blockIdx.x + gx * blockIdx.y;
  int cpx = nwg >> 3;
  int f2 = (flat & 7) * cpx + (flat >> 3);
  int bn = f2 % gx, bm = f2 / gx;
  int bz = blockIdx.z;
  if (SKIP == 1 && bn * 2 + 1 < bm) return;   // block's max t < min s -> all masked

  A  += (size_t)bz * sAb + (size_t)bm * 128 * lda;
  Bm += (size_t)bz * sBb + (size_t)bn * 256 * ldb;

  int tid = threadIdx.x;
  int lane = tid & 63, wid = tid >> 6;
  int wr = wid >> 2, wc = wid & 3;
  int lo = lane & 15, hi = lane >> 4;
  int rl0 = tid >> 3;
  int ce = 8 * ((tid & 7) ^ (rl0 & 7));   // pre-swizzled source chunk

  int nt = K / 64;
  if (SKIP == 2) nt = (bm + 1) * 2;       // kt = (bm+1)*128

  bf16x8 af[4][2], bg[4][2];
  f32x4 acc[4][4] = {};

  // prologue: tiles 0 and 1 fully staged; wait down to 6 -> tile0 resident
  STGTILE(0, 0);
  STGTILE(1, 1);
  VM6_; BAR_;

  int cur = 0;
  for (int t = 0; t < nt - 2; t++) {
    const unsigned short* bA = smem + cur * 24576;
    const unsigned short* bB = bA + 8192;
    LOADFRAGS(bA, bB)
    int b2 = cur + 2; if (b2 >= 3) b2 -= 3;
    STGTILE(t + 2, b2);
    MFMA32_
    VM6_; BAR_;
    cur = (cur + 1 == 3) ? 0 : cur + 1;
  }
  { // t = nt-2: no more staging; full drain so tile nt-1 is resident
    const unsigned short* bA = smem + cur * 24576;
    const unsigned short* bB = bA + 8192;
    LOADFRAGS(bA, bB)
    MFMA32_
    VM0_; BAR_;
    cur = (cur + 1 == 3) ? 0 : cur + 1;
  }
  { // t = nt-1: pure compute
    const unsigned short* bA = smem + cur * 24576;
    const unsigned short* bB = bA + 8192;
    LOADFRAGS(bA, bB)
    MFMA32_
  }

  // ---------------- epilogue: LDS retile -> coalesced 16B stores ----------------
  __syncthreads();
  int row0 = bm * 128, col0 = bn * 256;
  size_t coff = (size_t)bz * sCb;

  if (OMODE == 1) {
    unsigned short* ep = smem;   // [128][264] padded
    #pragma unroll
    for (int n = 0; n < 4; n++) {
      int cl = wc * 64 + n * 16 + lo;
      float bv = BIAS ? bias[col0 + cl] : 0.f;
      #pragma unroll
      for (int m = 0; m < 4; m++) {
        int rl = wr * 64 + m * 16 + hi * 4;
        #pragma unroll
        for (int j = 0; j < 4; j++)
          ep[(rl + j) * 264 + cl] = f2b(acc[m][n][j] + bv);
      }
    }
    __syncthreads();
    #pragma unroll
    for (int it = 0; it < 8; it++) {
      int idx = it * 512 + tid, r = idx >> 5, c = idx & 31;
      *(uint4*)(Cb + coff + (size_t)(row0 + r) * N + col0 + c * 8) =
          *(const uint4*)(ep + r * 264 + c * 8);
    }
  } else if (OMODE == 2) {
    float* ep = (float*)smem;    // [64][260] padded
    #pragma unroll
    for (int half = 0; half < 2; half++) {
      __syncthreads();
      if (wr == half) {
        #pragma unroll
        for (int n = 0; n < 4; n++) {
          int cl = wc * 64 + n * 16 + lo;
          #pragma unroll
          for (int m = 0; m < 4; m++) {
            int rl = m * 16 + hi * 4;
            #pragma unroll
            for (int j = 0; j < 4; j++) ep[(rl + j) * 260 + cl] = acc[m][n][j];
          }
        }
      }
      __syncthreads();
      #pragma unroll
      for (int it = 0; it < 8; it++) {
        int idx = it * 512 + tid, r = idx >> 6, c = idx & 63;
        *(float4*)(Cf + coff + (size_t)(row0 + half * 64 + r) * N + col0 + c * 4) =
            *(const float4*)(ep + r * 260 + c * 4);
      }
    }
  } else {   // OMODE == 4: out[b][d][t] = acc + m[b][t][d], transposed coalesced write
    float* ep = (float*)smem;    // [128 d][132 t] padded
    #pragma unroll
    for (int half = 0; half < 2; half++) {
      __syncthreads();
      if ((wc >> 1) == half) {
        #pragma unroll
        for (int n = 0; n < 4; n++) {
          int cl = wc * 64 + n * 16 + lo;
          #pragma unroll
          for (int m = 0; m < 4; m++) {
            int rl = wr * 64 + m * 16 + hi * 4;
            #pragma unroll
            for (int j = 0; j < 4; j++) {
              float v = acc[m][n][j] +
                        b2f(mres[((size_t)bz * T_DIM + row0 + rl + j) * D_DIM + col0 + cl]);
              ep[(cl & 127) * 132 + rl + j] = v;
            }
          }
        }
      }
      __syncthreads();
      #pragma unroll
      for (int it = 0; it < 8; it++) {
        int idx = it * 512 + tid, r = idx >> 5, c = idx & 31;
        *(float4*)(Cf + ((size_t)bz * D_DIM + col0 + half * 128 + r) * T_DIM + row0 + c * 4) =
            *(const float4*)(ep + r * 132 + c * 4);
      }
    }
  }
}

// ---------------- softmax stats over rows of logitsT (= axis-1 of logits) ----------------
__device__ __forceinline__ float wred_max(float v) {
  #pragma unroll
  for (int o = 32; o > 0; o >>= 1) v = fmaxf(v, __shfl_down(v, o, 64));
  return v;
}
__device__ __forceinline__ float wred_sum(float v) {
  #pragma unroll
  for (int o = 32; o > 0; o >>= 1) v += __shfl_down(v, o, 64);
  return v;
}

__global__ __launch_bounds__(256) void softmax_stats_kernel(const float* __restrict__ lg,
                                                            float* __restrict__ smax,
                                                            float* __restrict__ sinv) {
  __shared__ float sb[4];
  int row = blockIdx.x;            // b*T + s
  int s = row & (T_DIM - 1);
  int t0 = (s >> 8) << 8;          // causal: only t >= s contribute; 256-aligned start
  const float* Lr = lg + (size_t)row * T_DIM;
  float mx = -3.4e38f;
  for (int t = t0 + threadIdx.x; t < T_DIM; t += 256)
    if (t >= s) mx = fmaxf(mx, Lr[t]);
  mx = wred_max(mx);
  if ((threadIdx.x & 63) == 0) sb[threadIdx.x >> 6] = mx;
  __syncthreads();
  mx = fmaxf(fmaxf(sb[0], sb[1]), fmaxf(sb[2], sb[3]));
  __syncthreads();
  float sum = 0.f;
  for (int t = t0 + threadIdx.x; t < T_DIM; t += 256)
    if (t >= s) sum += __expf(Lr[t] - mx);
  sum = wred_sum(sum);
  if ((threadIdx.x & 63) == 0) sb[threadIdx.x >> 6] = sum;
  __syncthreads();
  if (threadIdx.x == 0) {
    float tot = sb[0] + sb[1] + sb[2] + sb[3];
    smax[row] = mx;
    sinv[row] = 1.0f / (tot * 32.0f);   // fold 1/sqrt(D)=1/32 into the normalizer
  }
}

// ---------------- normalize + transpose: probs[t][s] bf16 from logitsT[s][t] ----------------
__global__ __launch_bounds__(256) void probs_kernel(const float* __restrict__ lg,
                                                    const float* __restrict__ smax,
                                                    const float* __restrict__ sinv,
                                                    unsigned short* __restrict__ probs) {
  int bz = blockIdx.z;
  int t0 = blockIdx.x * 32, s0 = blockIdx.y * 32;
  if (s0 >= (((t0 >> 7) + 1) << 7)) return;   // never read by the K-limited PV GEMM (128-tiles)
  __shared__ float tile[32][33];
  int tx = threadIdx.x & 31, ty = threadIdx.x >> 5;
  const float* L = lg + (size_t)bz * T_DIM * T_DIM;
  #pragma unroll
  for (int i = 0; i < 32; i += 8)
    tile[ty + i][tx] = L[(size_t)(s0 + ty + i) * T_DIM + (t0 + tx)];
  __syncthreads();
  unsigned short* P = probs + (size_t)bz * T_DIM * T_DIM;
  #pragma unroll
  for (int i = 0; i < 32; i += 8) {
    int t = t0 + ty + i, s = s0 + tx;
    float x = tile[tx][ty + i];
    float p = (t >= s) ? __expf(x - smax[bz * T_DIM + s]) * sinv[bz * T_DIM + s] : 0.f;
    P[(size_t)t * T_DIM + s] = f2b(p);
  }
}

extern "C" void kernel_launch(void* const* d_in, const int* in_sizes, int n_in,
                              void* d_out, int out_size, void* d_ws, size_t ws_size,
                              hipStream_t stream) {
  const float* minibatch = (const float*)d_in[0];
  const float* emb_w   = (const float*)d_in[1];
  const float* emb_b   = (const float*)d_in[2];
  const float* key_w   = (const float*)d_in[3];
  const float* key_b   = (const float*)d_in[4];
  const float* query_w = (const float*)d_in[5];
  const float* query_b = (const float*)d_in[6];
  const float* value_w = (const float*)d_in[7];
  const float* value_b = (const float*)d_in[8];
  float* out = (float*)d_out;

  char* ws = (char*)d_ws;
  const size_t MB = 1ull << 20;
  unsigned short* wbf_emb = (unsigned short*)(ws + 0 * MB);    // 2 MB
  unsigned short* wbf_kqv = (unsigned short*)(ws + 2 * MB);    // 6 MB [key|query|value]
  float*          kqv_b   = (float*)(ws + 8 * MB);             // 12 KB
  unsigned short* m_bf    = (unsigned short*)(ws + 9 * MB);    // 16 MB, live to end
  unsigned short* KQV     = (unsigned short*)(ws + 25 * MB);   // 48 MB (dead after logits)
  unsigned short* VT_bf   = (unsigned short*)(ws + 73 * MB);   // 16 MB
  float*          logitsT = (float*)(ws + 89 * MB);            // 64 MB
  unsigned short* xT      = (unsigned short*)(ws + 153 * MB);  // 16 MB (dead after emb GEMM)
  unsigned short* probs   = (unsigned short*)(ws + 153 * MB);  // 32 MB, aliases xT
  float*          smax    = (float*)(ws + 186 * MB);
  float*          sinv    = (float*)(ws + 186 * MB + 32768);

  const int BT = B_DIM * T_DIM;   // 8192
  const size_t TT = (size_t)T_DIM * T_DIM;

  // 1) weights -> bf16 + bias concat (single launch)
  prep_kernel<<<4097, 256, 0, stream>>>(emb_w, key_w, query_w, value_w,
                                        key_b, query_b, value_b,
                                        wbf_emb, wbf_kqv, kqv_b);

  // 2) xT[b][t][h] = minibatch[b][h][t], bf16
  transpose_kernel<float><<<dim3(T_DIM / 32, H_DIM / 32, B_DIM), 256, 0, stream>>>(
      minibatch, xT, T_DIM, (size_t)H_DIM * T_DIM, H_DIM, (size_t)T_DIM * H_DIM);

  // 3) m = xT @ emb_w^T + emb_b  (bf16)  -- 256 blocks exact
  gemm8_kernel<1, true, 0><<<dim3(D_DIM / 256, BT / 128, 1), 512, 0, stream>>>(
      xT, wbf_emb, emb_b, nullptr, m_bf, nullptr, D_DIM, H_DIM, H_DIM, H_DIM, 0, 0, 0);

  // 4) KQV = m @ [Wk;Wq;Wv]^T + b  (bf16, [8192][3072]) -- 768 blocks = 3 exact waves
  gemm8_kernel<1, true, 0><<<dim3(3072 / 256, BT / 128, 1), 512, 0, stream>>>(
      m_bf, wbf_kqv, kqv_b, nullptr, KQV, nullptr, 3072, D_DIM, D_DIM, D_DIM, 0, 0, 0);

  // 5) VT[b][d][t] = V[b][t][d]  (V = KQV cols 2048..3071)
  transpose_kernel<unsigned short><<<dim3(D_DIM / 32, T_DIM / 32, B_DIM), 256, 0, stream>>>(
      KQV + 2048, VT_bf, 3072, (size_t)T_DIM * 3072, T_DIM, (size_t)D_DIM * T_DIM);

  // 6) logitsT[b][s][t] = K[b,s]·Q[b,t]  (causal block skip)
  gemm8_kernel<2, false, 1><<<dim3(T_DIM / 256, T_DIM / 128, B_DIM), 512, 0, stream>>>(
      KQV, KQV + 1024, nullptr, logitsT, nullptr, nullptr, T_DIM, D_DIM, 3072, 3072,
      (size_t)T_DIM * 3072, (size_t)T_DIM * 3072, TT);

  // 7) column-softmax stats (per (b,s): max/sum over t >= s), fold 1/sqrt(D)
  softmax_stats_kernel<<<BT, 256, 0, stream>>>(logitsT, smax, sinv);

  // 8) probs[b][t][s] bf16, transposed
  probs_kernel<<<dim3(T_DIM / 32, T_DIM / 32, B_DIM), 256, 0, stream>>>(
      logitsT, smax, sinv, probs);

  // 9) fused PV + residual + output transpose: out[b][d][t] = sum_s probs*VT + m
  gemm8_kernel<4, false, 2><<<dim3(D_DIM / 256, T_DIM / 128, B_DIM), 512, 0, stream>>>(
      probs, VT_bf, nullptr, out, nullptr, m_bf, D_DIM, T_DIM, T_DIM, T_DIM,
      TT, (size_t)D_DIM * T_DIM, 0);
}